// Round 1
// 1504.230 us; speedup vs baseline: 1.3773x; 1.3773x over previous
//
#include <hip/hip_runtime.h>
#include <math.h>

#define BB 16
#define LL 48
#define HH 1024
#define NG4 4096      // 4*H
#define NG6 6144      // 6*H
#define K3H 3072      // 3*H
#define RANKH 128
#define MAXN 47       // max nodes per batch (len-1 <= 47)
#define TOTN (BB*MAXN)
#define MAXLVL 48
#define MAXNPL 384    // max nodes in one level

#define CH 20         // padded floats per 16-float k-chunk in scan LDS
#define HROW (64*CH)  // 1280 floats per m-row

typedef __attribute__((ext_vector_type(8))) short bf16x8;
typedef __attribute__((ext_vector_type(4))) float f32x4;

__device__ __forceinline__ float sigf(float x){ return 1.f/(1.f + expf(-x)); }

__device__ __forceinline__ unsigned short f2bf(float f){
  union { float f; unsigned u; } v; v.f = f;
  unsigned r = v.u + 0x7fff + ((v.u >> 16) & 1);
  return (unsigned short)(r >> 16);
}

// ---- LLC-coherent ops (device coherence point; bypass L1/L2, no allocate) ----
__device__ __forceinline__ void st_llc(float* p, float v){
  __hip_atomic_store(p, v, __ATOMIC_RELAXED, __HIP_MEMORY_SCOPE_AGENT);
}
__device__ __forceinline__ float ld_llc(const float* p){
  return __hip_atomic_load(p, __ATOMIC_RELAXED, __HIP_MEMORY_SCOPE_AGENT);
}
__device__ __forceinline__ f32x4 ld_llc4f(const float* p){
  f32x4 v;
  asm volatile("global_load_dwordx4 %0, %1, off sc0 sc1" : "=v"(v) : "v"(p));
  return v;
}
__device__ __forceinline__ void st_llc_u16(unsigned short* p, unsigned v){
  asm volatile("global_store_short %0, %1, off sc0 sc1" :: "v"(p), "v"(v) : "memory");
}
__device__ __forceinline__ void wait_vm0(){
  asm volatile("s_waitcnt vmcnt(0)" ::: "memory");
}

// Distributed-flag grid barrier: NO atomic RMW, NO writeback, NO invalidate.
// Each block stores flag[blockIdx]=p after vmcnt(0) (its LLC stores are ack'd);
// all 256 threads poll the 256 flags. Data crossing the barrier must use LLC
// ops (st_llc*) or be first-read-after-write (cached miss -> fresh LLC line).
// flags MUST be zeroed every launch (workspace re-poisoned to 0xAA).
__device__ __forceinline__ void flagbar(unsigned* flags, unsigned p, int* ldsok){
  wait_vm0();
  __syncthreads();
  if (threadIdx.x == 0)
    __hip_atomic_store(&flags[blockIdx.x], p, __ATOMIC_RELAXED, __HIP_MEMORY_SCOPE_AGENT);
  for (;;){
    unsigned f = __hip_atomic_load(&flags[threadIdx.x], __ATOMIC_RELAXED, __HIP_MEMORY_SCOPE_AGENT);
    int all4 = __all((int)(f >= p));
    if ((threadIdx.x & 63) == 0) ldsok[threadIdx.x >> 6] = all4;
    __syncthreads();
    if (ldsok[0] & ldsok[1] & ldsok[2] & ldsok[3]) break;
    __builtin_amdgcn_s_sleep(1);
    __syncthreads();
  }
}

// ---------------------------------------------------------------------------
// Zero flag arrays ([0..255]=scan, [256..511]=tree) + the zero dummy row.
__global__ __launch_bounds__(256) void k_init(unsigned* flags, unsigned short* zrow){
  int tid = threadIdx.x;
  flags[tid] = 0u;
  flags[256 + tid] = 0u;
  for (int i = tid; i < 1024; i += 256) zrow[i] = 0;
}

// ---------------------------------------------------------------------------
// fp32 -> bf16 (RNE), vectorized. n multiple of 1024.
__global__ __launch_bounds__(256) void k_cvt_bf16(const float* __restrict__ in,
    unsigned short* __restrict__ out, int n){
  int i = (blockIdx.x*256 + threadIdx.x)*4;
  if (i >= n) return;
  float4 v = *(const float4*)(in + i);
  ushort4 o;
  o.x = f2bf(v.x); o.y = f2bf(v.y); o.z = f2bf(v.z); o.w = f2bf(v.w);
  *(ushort4*)(out + i) = o;
}

// ---------------------------------------------------------------------------
// Generic 32x32 LDS-tiled transpose: out[C][R] = in[R][C]^T  (R1 only)
__global__ __launch_bounds__(256) void k_transpose(const float* __restrict__ in,
                                                   float* __restrict__ out, int R, int C){
  __shared__ float t[32][33];
  int bx = blockIdx.x*32, by = blockIdx.y*32;
  int x = threadIdx.x, y = threadIdx.y;   // block (32,8)
  #pragma unroll
  for (int i = 0; i < 32; i += 8){
    int r = by + y + i, c = bx + x;
    if (r < R && c < C) t[y+i][x] = in[(size_t)r*C + c];
  }
  __syncthreads();
  #pragma unroll
  for (int i = 0; i < 32; i += 8){
    int r = bx + y + i, c = by + x;       // out dims [C][R]
    if (r < C && c < R) out[(size_t)r*R + c] = t[x][y+i];
  }
}

// ---------------------------------------------------------------------------
// Gx[m][n] = sum_k se[m][k]*Wih[n][k] + bih[n] + bhh[n]   (fp32 — decision path)
__global__ __launch_bounds__(256) void k_gemm_gx(const float* __restrict__ A,
    const float* __restrict__ Bw, const float* __restrict__ bih,
    const float* __restrict__ bhh, float* __restrict__ Cout, int M, int N, int K){
  __shared__ float as[16][68];
  __shared__ float bs[16][68];
  int m0 = blockIdx.x*64, n0 = blockIdx.y*64;
  int tid = threadIdx.x;
  int mt = tid & 15, nt = tid >> 4;
  float acc[4][4] = {};
  for (int k0 = 0; k0 < K; k0 += 16){
    #pragma unroll
    for (int it = 0; it < 4; ++it){
      int idx = it*256 + tid;
      int kk = idx & 15, mm = idx >> 4;
      as[kk][mm] = A[(size_t)(m0+mm)*K + k0 + kk];
      bs[kk][mm] = Bw[(size_t)(n0+mm)*K + k0 + kk];
    }
    __syncthreads();
    #pragma unroll
    for (int kk = 0; kk < 16; ++kk){
      float a4[4], b4[4];
      #pragma unroll
      for (int i = 0; i < 4; ++i) a4[i] = as[kk][mt*4+i];
      #pragma unroll
      for (int i = 0; i < 4; ++i) b4[i] = bs[kk][nt*4+i];
      #pragma unroll
      for (int i = 0; i < 4; ++i)
        #pragma unroll
        for (int j2 = 0; j2 < 4; ++j2) acc[i][j2] += a4[i]*b4[j2];
    }
    __syncthreads();
  }
  #pragma unroll
  for (int i = 0; i < 4; ++i){
    int m = m0 + mt*4 + i;
    #pragma unroll
    for (int j2 = 0; j2 < 4; ++j2){
      int n = n0 + nt*4 + j2;
      Cout[(size_t)m*N + n] = acc[i][j2] + bih[n] + bhh[n];
    }
  }
}

// ---------------------------------------------------------------------------
// Gx [m][t][4096] -> Gxt [t][4096][m]  (for coalesced per-step gate reads)
__global__ __launch_bounds__(256) void k_gx_t(const float* __restrict__ Gx,
                                              float* __restrict__ Gxt){
  __shared__ float t2[16][257];
  int t = blockIdx.x;       // 48
  int rc = blockIdx.y;      // 16 chunks of 256 rows
  int tid = threadIdx.x;
  #pragma unroll
  for (int m = 0; m < 16; ++m)
    t2[m][tid] = Gx[((size_t)(m*48 + t))*4096 + rc*256 + tid];
  __syncthreads();
  int rl = tid >> 4, m = tid & 15;
  #pragma unroll
  for (int i = 0; i < 16; ++i){
    int r = rc*256 + i*16 + rl;
    Gxt[((size_t)t*4096 + r)*16 + m] = t2[m][i*16 + rl];
  }
}

// ---------------------------------------------------------------------------
// Persistent LSTM scan: 256 blocks x 256 threads, 1 block/CU.
// h exchanged through LLC; flag barrier (no RMW / wb / inv).
// Whh held in registers (w[4][16] per lane, lane=k-chunk of 16).
__global__ __launch_bounds__(256, 1) void k_lstm_scan(
    const float* __restrict__ Whh, const float* __restrict__ Gxt,
    float* __restrict__ hs, float* __restrict__ cs,
    unsigned short* __restrict__ hs_bf, unsigned* __restrict__ flags){
  __shared__ float smem[16*HROW];   // 80KB: h-stage; overlaid by reduce partials
  __shared__ float gbuf[4*64];
  __shared__ float cbuf[64];
  __shared__ int ldsok[4];
  int tid = threadIdx.x;
  int g = tid >> 6, kc = tid & 63;
  int j0 = blockIdx.x * 4;
  float w[4][16];
  #pragma unroll
  for (int jj = 0; jj < 4; ++jj){
    const float* src = Whh + (size_t)(g*1024 + j0 + jj)*1024 + kc*16;
    #pragma unroll
    for (int kk = 0; kk < 16; kk += 4){
      float4 v = *(const float4*)(src + kk);
      w[jj][kk]=v.x; w[jj][kk+1]=v.y; w[jj][kk+2]=v.z; w[jj][kk+3]=v.w;
    }
  }
  if (tid < 64) cbuf[tid] = 0.f;
  for (int t = 0; t < LL; ++t){
    float G = 0.f;
    if (t > 0){
      // batched LLC loads of h_{t-1}: 16 dwordx4 in flight, one vmcnt
      f32x4 hv[16];
      #pragma unroll
      for (int m = 0; m < 16; ++m)
        hv[m] = ld_llc4f(hs + ((size_t)(m*LL + t-1))*HH + (tid<<2));
      wait_vm0();
      #pragma unroll
      for (int m = 0; m < 16; ++m)
        *(f32x4*)&smem[m*HROW + (tid>>2)*CH + (tid&3)*4] = hv[m];
      __syncthreads();
      float acc[4][16];
      #pragma unroll 4
      for (int m = 0; m < 16; ++m){
        const float* hb = &smem[m*HROW + kc*CH];
        float4 h0 = *(const float4*)(hb);
        float4 h1 = *(const float4*)(hb+4);
        float4 h2 = *(const float4*)(hb+8);
        float4 h3 = *(const float4*)(hb+12);
        #pragma unroll
        for (int jj = 0; jj < 4; ++jj){
          float s = w[jj][0]*h0.x + w[jj][1]*h0.y + w[jj][2]*h0.z + w[jj][3]*h0.w
                  + w[jj][4]*h1.x + w[jj][5]*h1.y + w[jj][6]*h1.z + w[jj][7]*h1.w
                  + w[jj][8]*h2.x + w[jj][9]*h2.y + w[jj][10]*h2.z + w[jj][11]*h2.w
                  + w[jj][12]*h3.x + w[jj][13]*h3.y + w[jj][14]*h3.z + w[jj][15]*h3.w;
          acc[jj][m] = s;
        }
      }
      __syncthreads();   // hsm reads done; smem reused as reduce partials
      #pragma unroll
      for (int m = 0; m < 16; ++m){
        float4 v;
        v.x = acc[0][m]; v.y = acc[1][m]; v.z = acc[2][m]; v.w = acc[3][m];
        *(float4*)&smem[(size_t)(g*64 + kc)*68 + m*4] = v;
      }
      __syncthreads();
      {
        float s0=0.f,s1=0.f,s2=0.f,s3=0.f;
        #pragma unroll 4
        for (int l = 0; l < 64; l += 4){
          s0 += smem[(size_t)(g*64 + l  )*68 + kc];
          s1 += smem[(size_t)(g*64 + l+1)*68 + kc];
          s2 += smem[(size_t)(g*64 + l+2)*68 + kc];
          s3 += smem[(size_t)(g*64 + l+3)*68 + kc];
        }
        G = (s0+s1)+(s2+s3);
      }
    }
    gbuf[g*64 + kc] = G;
    __syncthreads();
    if (g == 0){
      int o = kc;               // o = m*4 + jj
      int jj = o & 3, m = o >> 2;
      size_t gxb = ((size_t)t*NG4 + j0 + jj)*16 + m;
      float gi = gbuf[0*64 + o] + Gxt[gxb + 0*16384];
      float gf = gbuf[1*64 + o] + Gxt[gxb + 1*16384];
      float gu = gbuf[2*64 + o] + Gxt[gxb + 2*16384];
      float go = gbuf[3*64 + o] + Gxt[gxb + 3*16384];
      float cp = cbuf[o];
      float c = sigf(gf)*cp + sigf(gi)*tanhf(gu);
      float h = sigf(go)*tanhf(c);
      cbuf[o] = c;
      size_t oidx = ((size_t)(m*LL + t))*HH + j0 + jj;
      st_llc(&hs[oidx], h);     // LLC write-through: visible without fences
      cs[oidx] = c;             // consumed after kernel boundary only
      hs_bf[oidx] = f2bf(h);    // consumed after kernel boundary only
    }
    if (t < LL-1)
      flagbar(flags, (unsigned)(t+1), ldsok);
  }
}

// ---------------------------------------------------------------------------
// Per-position rank-MLP score + gumbel noise (fp32 — decision path).
__global__ __launch_bounds__(128) void k_score(const float* __restrict__ R1t,
    const float* __restrict__ R2, const float* __restrict__ hs,
    const float* __restrict__ gumbel_u, float* __restrict__ score,
    float* __restrict__ snoisy){
  __shared__ float hsm[HH];
  __shared__ float red[128];
  int bt = blockIdx.x;
  int tid = threadIdx.x;
  for (int i = tid; i < HH; i += 128) hsm[i] = hs[(size_t)bt*HH + i];
  __syncthreads();
  float acc = 0.f;
  for (int k = 0; k < HH; ++k) acc += R1t[(size_t)k*RANKH + tid] * hsm[k];
  red[tid] = fmaxf(acc, 0.f) * R2[tid];
  __syncthreads();
  for (int s = 64; s > 0; s >>= 1){
    if (tid < s) red[tid] += red[tid+s];
    __syncthreads();
  }
  if (tid == 0){
    float s = red[0];
    float u = gumbel_u[bt];
    float noise = -logf(-logf(u));
    score[bt]  = s;
    snoisy[bt] = s + noise;
  }
}

// ---------------------------------------------------------------------------
// Build the tree structure for all batches. 1 block, 64 threads.
// level_count[0] <- number of levels (max height).
__global__ __launch_bounds__(64) void k_build(const float* __restrict__ score,
    const float* __restrict__ snoisy, const int* __restrict__ length,
    int* __restrict__ node_l, int* __restrict__ node_r, int* __restrict__ node_x,
    int* __restrict__ node_lvl, int* __restrict__ node_b, int* __restrict__ node_root,
    int* __restrict__ level_count, int* __restrict__ level_off, int* __restrict__ order){
  __shared__ float sc[BB*LL], sn[BB*LL];
  __shared__ int lcount[MAXLVL+1], lcur[MAXLVL+1], loff[MAXLVL+1];
  __shared__ int percnt[BB];
  int tid = threadIdx.x;
  for (int i = tid; i < BB*LL; i += 64){ sc[i] = score[i]; sn[i] = snoisy[i]; }
  for (int i = tid; i <= MAXLVL; i += 64){ lcount[i] = 0; lcur[i] = 0; }
  __syncthreads();
  if (tid < BB){
    int b = tid;
    int len = length[b];
    if (len > LL) len = LL;
    int qs[MAXN], qe[MAXN], qn[MAXN];
    int qh = 0, qt = 0, cnt = 0;
    int rootn = cnt++;
    qs[qt] = 0; qe[qt] = len; qn[qt] = rootn; qt++;
    while (qh < qt){
      int s0 = qs[qh], e0 = qe[qh], nid = qn[qh]; qh++;
      float best = sc[b*LL + s0]; int pos = s0;
      for (int t2 = s0+1; t2 < e0; ++t2){
        float v = sc[b*LL + t2];
        if (v > best){ best = v; pos = t2; }
      }
      float bestn = sn[b*LL + s0]; int js = s0;
      for (int t2 = s0+1; t2 < e0; ++t2){
        float v = sn[b*LL + t2];
        if (v > bestn){ bestn = v; js = t2; }
      }
      int gid = b*MAXN + nid;
      node_x[gid] = js;
      node_b[gid] = b;
      node_root[gid] = (nid == 0) ? 1 : 0;
      int ln = pos - s0, enc_l, enc_r;
      if (ln <= 0) enc_l = -1;
      else if (ln == 1) enc_l = 10000 + s0;
      else { int c2 = cnt++; enc_l = b*MAXN + c2; qs[qt]=s0; qe[qt]=pos; qn[qt]=c2; qt++; }
      int rn = e0 - (pos+1);
      if (rn <= 0) enc_r = -1;
      else if (rn == 1) enc_r = 10000 + (pos+1);
      else { int c2 = cnt++; enc_r = b*MAXN + c2; qs[qt]=pos+1; qe[qt]=e0; qn[qt]=c2; qt++; }
      node_l[gid] = enc_l; node_r[gid] = enc_r;
    }
    for (int i = cnt-1; i >= 0; --i){
      int gid = b*MAXN + i;
      int el = node_l[gid], er = node_r[gid];
      int llv = (el >= 0 && el < 10000) ? node_lvl[el] : 0;
      int rlv = (er >= 0 && er < 10000) ? node_lvl[er] : 0;
      node_lvl[gid] = 1 + (llv > rlv ? llv : rlv);
    }
    for (int i = 0; i < cnt; ++i) atomicAdd(&lcount[node_lvl[b*MAXN + i]], 1);
    percnt[b] = cnt;
  }
  __syncthreads();
  if (tid == 0){
    int off = 0, nlev = 0;
    for (int lv = 1; lv <= MAXLVL; ++lv){
      loff[lv] = off;
      level_off[lv] = off;
      level_count[lv] = lcount[lv];
      if (lcount[lv] > 0) nlev = lv;
      off += lcount[lv];
    }
    level_count[0] = nlev;
  }
  __syncthreads();
  if (tid < BB){
    int b = tid;
    int cnt = percnt[b];
    for (int i = 0; i < cnt; ++i){
      int gid = b*MAXN + i;
      int lv = node_lvl[gid];
      int p = atomicAdd(&lcur[lv], 1);
      order[loff[lv] + p] = gid;
    }
  }
}

// ---------------------------------------------------------------------------
// Persistent tree composition, flag barriers, NO wb/inv.
// NEW SCHEME: Wc is LDS-RESIDENT. Each of the 256 blocks owns 24 Wc rows
// (24 x 3072 bf16 = 144KB, loaded ONCE, XOR-swizzled to kill the 6144B-stride
// bank conflict). Per level every block computes its 24 gate columns for ALL
// nodes of the level: A-frags (child h rows) are small L2-broadcast reads,
// B-frags come from LDS, so the per-level 37.7MB Wc re-stream is gone.
// 24 rows = one full 16-row MFMA n-tile + one 8-row half-tile (B rows
// duplicated via (fr&7); upper 8 output cols of the half-tile discarded).
// Coherence protocol unchanged:
//  - gates: LLC stores (A) -> LLC loads (B)
//  - nodeH_bf / nodeC: LLC stores (B) -> normal cached first-reads at later
//    levels (row written once, never cached before its first read)
//  - Wc_bf / hs_bf / order / node_*: read-only, cached.
__global__ __launch_bounds__(256, 1) void k_tree(
    const unsigned short* __restrict__ Wc_bf,
    const unsigned short* __restrict__ hs_bf,
    unsigned short* __restrict__ nodeH_bf,
    const unsigned short* __restrict__ zrow,
    const float* __restrict__ bc, const float* __restrict__ cs,
    float* __restrict__ nodeC,
    const int* __restrict__ node_l, const int* __restrict__ node_r,
    const int* __restrict__ node_x, const int* __restrict__ node_b,
    const int* __restrict__ node_root, const int* __restrict__ level_count,
    const int* __restrict__ level_off, const int* __restrict__ order,
    float* __restrict__ gates, float* __restrict__ out,
    unsigned* __restrict__ flags){
  __shared__ __align__(16) unsigned char wlds[24*6144];   // 144KB Wc slice
  __shared__ int ldsok[4];
  int tid = threadIdx.x;
  int lane = tid & 63;
  int wave = tid >> 6;
  int fr = lane & 15;          // fragment row (A: node slot, B: Wc row)
  int fkq = lane >> 4;         // k-quarter 0..3
  int fk  = fkq * 8;           // element offset within 32-elem k-chunk
  int fkb = fkq * 16;          // byte offset
  int swz = (fr & 7) << 4;     // XOR swizzle (G4: row-major stride-6144B tile)
  int base0 = fr * 6144;               // n-tile 0: rows 0..15
  int base1 = (16 + (fr & 7)) * 6144;  // n-tile 1: rows 16..23 (dup for fr>=8)
  int rg24 = blockIdx.x * 24;  // this block's 24 Wc rows / gate columns

  // ---- one-time: stage 24 Wc rows into LDS, swizzled ----
  for (int i = tid; i < 24*384; i += 256){
    int row = i / 384;
    int ch  = i - row*384;     // 16B chunk within row
    uint4 v = *(const uint4*)(Wc_bf + (size_t)(rg24 + row)*K3H + ch*8);
    *(uint4*)(wlds + row*6144 + ((ch*16) ^ ((row & 7) << 4))) = v;
  }
  __syncthreads();

  int nlev = level_count[0];
  unsigned ph = 0;
  for (int lvl = 1; lvl <= nlev; ++lvl){
    int n = level_count[lvl];
    int loffv = level_off[lvl];
    // ---- Phase A: all nodes x this block's 24 Wc rows, B from LDS ----
    int mtiles = (n + 15) >> 4;
    for (int mt = wave; mt < mtiles; mt += 4){
      int slot = mt*16 + fr;
      const unsigned short *pa0, *pa1, *pa2;
      if (slot < n){
        int gid = order[loffv + slot];
        int b = node_b[gid];
        int el = node_l[gid], er = node_r[gid], xt = node_x[gid];
        pa0 = (el < 0) ? zrow : (el >= 10000 ? hs_bf + (size_t)(b*LL + (el-10000))*HH
                                             : nodeH_bf + (size_t)el*HH);
        pa1 = (er < 0) ? zrow : (er >= 10000 ? hs_bf + (size_t)(b*LL + (er-10000))*HH
                                             : nodeH_bf + (size_t)er*HH);
        pa2 = hs_bf + (size_t)(b*LL + xt)*HH;
      } else { pa0 = zrow; pa1 = zrow; pa2 = zrow; }
      const unsigned short* pa[3] = {pa0, pa1, pa2};
      f32x4 acc0 = {0.f,0.f,0.f,0.f};
      f32x4 acc1 = {0.f,0.f,0.f,0.f};
      #pragma unroll
      for (int part = 0; part < 3; ++part){
        const unsigned short* ap = pa[part] + fk;
        #pragma unroll 8
        for (int kcc = 0; kcc < 1024; kcc += 32){
          bf16x8 a = *(const bf16x8*)(ap + kcc);
          int xb = part*2048 + kcc*2 + fkb;
          bf16x8 b0 = *(const bf16x8*)(wlds + base0 + (xb ^ swz));
          bf16x8 b1 = *(const bf16x8*)(wlds + base1 + (xb ^ swz));
          acc0 = __builtin_amdgcn_mfma_f32_16x16x32_bf16(a, b0, acc0, 0, 0, 0);
          acc1 = __builtin_amdgcn_mfma_f32_16x16x32_bf16(a, b1, acc1, 0, 0, 0);
        }
      }
      int m0 = mt*16 + fkq*4;
      #pragma unroll
      for (int r = 0; r < 4; ++r){
        int m = m0 + r;
        if (m < n){
          st_llc(&gates[(size_t)m*NG6 + rg24 + fr], acc0[r]);
          if (fr < 8)
            st_llc(&gates[(size_t)m*NG6 + rg24 + 16 + fr], acc1[r]);
        }
      }
    }
    ph++;
    flagbar(flags, ph, ldsok);
    // ---- Phase B: epilogue ----
    int items = n * 4;
    for (int it = blockIdx.x; it < items; it += 256){
      int ns = it >> 2;
      int j = (it & 3)*256 + tid;
      int gid = order[loffv + ns];
      int b = node_b[gid];
      int el = node_l[gid], er = node_r[gid], xt = node_x[gid];
      float gg[6];
      #pragma unroll
      for (int q = 0; q < 6; ++q)
        gg[q] = bc[q*HH + j] + ld_llc(&gates[(size_t)ns*NG6 + q*HH + j]);
      float lc = (el < 0) ? 0.f : (el >= 10000 ? cs[(size_t)(b*LL + (el-10000))*HH + j]
                                               : nodeC[(size_t)el*HH + j]);
      float rc = (er < 0) ? 0.f : (er >= 10000 ? cs[(size_t)(b*LL + (er-10000))*HH + j]
                                               : nodeC[(size_t)er*HH + j]);
      float xc = cs[(size_t)(b*LL + xt)*HH + j];
      float c = sigf(gg[0])*tanhf(gg[4]) + sigf(gg[1])*lc + sigf(gg[2])*rc + sigf(gg[3])*xc;
      float h = sigf(gg[5])*tanhf(c);
      st_llc_u16(&nodeH_bf[(size_t)gid*HH + j], (unsigned)f2bf(h));
      st_llc(&nodeC[(size_t)gid*HH + j], c);
      if (node_root[gid]){
        out[(size_t)b*HH + j] = h;
        out[(size_t)BB*HH + (size_t)b*HH + j] = c;
      }
    }
    if (lvl < nlev){
      ph++;
      flagbar(flags, ph, ldsok);
    }
  }
}

// ---------------------------------------------------------------------------
extern "C" void kernel_launch(void* const* d_in, const int* in_sizes, int n_in,
                              void* d_out, int out_size, void* d_ws, size_t ws_size,
                              hipStream_t stream){
  const float* se  = (const float*)d_in[0];
  const float* gu  = (const float*)d_in[1];
  const float* Wih = (const float*)d_in[2];
  const float* Whh = (const float*)d_in[3];
  const float* bih = (const float*)d_in[4];
  const float* bhh = (const float*)d_in[5];
  const float* R1  = (const float*)d_in[6];
  const float* R2  = (const float*)d_in[7];
  const float* Wc  = (const float*)d_in[8];
  const float* bc  = (const float*)d_in[9];
  const int*   len = (const int*)d_in[10];
  float* out = (float*)d_out;                 // [2,16,1024] fp32

  float* ws = (float*)d_ws;
  size_t off = 0;
  float* R1t   = ws + off; off += (size_t)HH*RANKH;
  float* Gx    = ws + off; off += (size_t)BB*LL*NG4;     // [m][t][4096]
  float* Gxt   = ws + off; off += (size_t)BB*LL*NG4;     // [t][4096][m]
  float* hs    = ws + off; off += (size_t)BB*LL*HH;
  float* cs    = ws + off; off += (size_t)BB*LL*HH;
  float* nodeC = ws + off; off += (size_t)TOTN*HH;
  float* gates = ws + off; off += (size_t)MAXNPL*NG6;
  unsigned short* Wc_bf    = (unsigned short*)(ws + off); off += (size_t)NG6*K3H/2;
  unsigned short* hs_bf    = (unsigned short*)(ws + off); off += (size_t)BB*LL*HH/2;
  unsigned short* nodeH_bf = (unsigned short*)(ws + off); off += (size_t)TOTN*HH/2 + 512;
  unsigned short* zrow     = (unsigned short*)(ws + off); off += 512;  // 1024 zero bf16
  float* score = ws + off; off += 1024;
  float* snoi  = ws + off; off += 1024;
  unsigned* flags = (unsigned*)(ws + off); off += 512;   // [0..255] scan, [256..511] tree
  int* ib = (int*)(ws + off);
  int* node_l    = ib; ib += 768;
  int* node_r    = ib; ib += 768;
  int* node_x    = ib; ib += 768;
  int* node_lvl  = ib; ib += 768;
  int* node_b    = ib; ib += 768;
  int* node_root = ib; ib += 768;
  int* level_count = ib; ib += 64;
  int* level_off   = ib; ib += 64;
  int* order       = ib; ib += 768;

  // 0. zero flag arrays + dummy zero row (ws poisoned every launch)
  k_init<<<1, 256, 0, stream>>>(flags, zrow);
  // 1. R1 transpose + Wc bf16 conversion
  k_transpose<<<dim3(32, 4), dim3(32, 8), 0, stream>>>(R1, R1t, RANKH, HH);
  k_cvt_bf16<<<(NG6*K3H)/1024, 256, 0, stream>>>(Wc, Wc_bf, NG6*K3H);
  // 2. input-side gate GEMM (+ both biases), then transpose for the scan
  k_gemm_gx<<<dim3(12, 64), 256, 0, stream>>>(se, Wih, bih, bhh, Gx, BB*LL, NG4, HH);
  k_gx_t<<<dim3(48, 16), 256, 0, stream>>>(Gx, Gxt);
  // 3. persistent recurrent LSTM scan (48 steps, flag barriers)
  k_lstm_scan<<<256, 256, 0, stream>>>(Whh, Gxt, hs, cs, hs_bf, flags);
  // 4. per-position scores + gumbel noise (fp32)
  k_score<<<BB*LL, 128, 0, stream>>>(R1t, R2, hs, gu, score, snoi);
  // 5. tree structure
  k_build<<<1, 64, 0, stream>>>(score, snoi, len, node_l, node_r, node_x,
                                node_lvl, node_b, node_root,
                                level_count, level_off, order);
  // 6. persistent level-by-level nary composition (LDS-resident Wc)
  k_tree<<<256, 256, 0, stream>>>(Wc_bf, hs_bf, nodeH_bf, zrow, bc, cs, nodeC,
                                  node_l, node_r, node_x, node_b, node_root,
                                  level_count, level_off, order,
                                  gates, out, flags + 256);
}

// Round 2
// 1445.177 us; speedup vs baseline: 1.4336x; 1.0409x over previous
//
#include <hip/hip_runtime.h>
#include <math.h>

#define BB 16
#define LL 48
#define HH 1024
#define NG4 4096      // 4*H
#define NG6 6144      // 6*H
#define K3H 3072      // 3*H
#define RANKH 128
#define MAXN 47       // max nodes per batch (len-1 <= 47)
#define TOTN (BB*MAXN)
#define MAXLVL 48
#define MAXNPL 384    // max nodes in one level

typedef __attribute__((ext_vector_type(8))) short bf16x8;
typedef __attribute__((ext_vector_type(4))) float f32x4;

__device__ __forceinline__ float sigf(float x){ return 1.f/(1.f + expf(-x)); }

__device__ __forceinline__ unsigned short f2bf(float f){
  union { float f; unsigned u; } v; v.f = f;
  unsigned r = v.u + 0x7fff + ((v.u >> 16) & 1);
  return (unsigned short)(r >> 16);
}

// ---- LLC-coherent ops (device coherence point; bypass L1/L2, no allocate) ----
__device__ __forceinline__ void st_llc(float* p, float v){
  __hip_atomic_store(p, v, __ATOMIC_RELAXED, __HIP_MEMORY_SCOPE_AGENT);
}
__device__ __forceinline__ float ld_llc(const float* p){
  return __hip_atomic_load(p, __ATOMIC_RELAXED, __HIP_MEMORY_SCOPE_AGENT);
}
__device__ __forceinline__ f32x4 ld_llc4f(const float* p){
  f32x4 v;
  asm volatile("global_load_dwordx4 %0, %1, off sc0 sc1" : "=v"(v) : "v"(p));
  return v;
}
__device__ __forceinline__ void st_llc_u16(unsigned short* p, unsigned v){
  asm volatile("global_store_short %0, %1, off sc0 sc1" :: "v"(p), "v"(v) : "memory");
}
__device__ __forceinline__ void st_llc_u8(unsigned char* p, unsigned v){
  asm volatile("global_store_byte %0, %1, off sc0 sc1" :: "v"(p), "v"(v) : "memory");
}
__device__ __forceinline__ void wait_vm0(){
  asm volatile("s_waitcnt vmcnt(0)" ::: "memory");
}

// Distributed-flag grid barrier: NO atomic RMW, NO writeback, NO invalidate.
// BYTE flags (256B = few cache lines); only wave 0 polls (one dword load per
// lane covers 4 block-flags -> all 256 flags in ONE wave-load), result is
// broadcast to the other waves through LDS. Each block stores its flag byte
// after vmcnt(0) (its LLC stores are ack'd). Data crossing the barrier must
// use LLC ops (st_llc*) or be first-read-after-write.
// Phase values must stay < 256 (max used here is ~94).
// flags MUST be zeroed every launch (workspace re-poisoned to 0xAA).
__device__ __forceinline__ void flagbar(unsigned char* flags, unsigned p, int* ldsok){
  wait_vm0();
  __syncthreads();
  int tid = threadIdx.x;
  if (tid == 0)
    st_llc_u8(&flags[blockIdx.x], p);
  for (;;){
    if (tid < 64){
      unsigned v;
      asm volatile("global_load_dword %0, %1, off sc0 sc1"
                   : "=v"(v) : "v"((const unsigned*)flags + tid));
      wait_vm0();
      int ok = (int)(((v      ) & 255u) >= p) & (int)(((v >>  8) & 255u) >= p)
             & (int)(((v >> 16) & 255u) >= p) & (int)(((v >> 24)       ) >= p);
      int all64 = __all(ok);
      if (tid == 0) ldsok[0] = all64;
    }
    __syncthreads();
    if (ldsok[0]) break;
    __builtin_amdgcn_s_sleep(1);
    __syncthreads();
  }
}

// ---------------------------------------------------------------------------
// Zero flag arrays (bytes [0..255]=scan at uint ofs 0, [1024..1279]=tree at
// uint ofs 256) + the zero dummy row.
__global__ __launch_bounds__(256) void k_init(unsigned* flags, unsigned short* zrow){
  int tid = threadIdx.x;
  flags[tid] = 0u;
  flags[256 + tid] = 0u;
  for (int i = tid; i < 1024; i += 256) zrow[i] = 0;
}

// ---------------------------------------------------------------------------
// fp32 -> bf16 (RNE), vectorized. n multiple of 1024.
__global__ __launch_bounds__(256) void k_cvt_bf16(const float* __restrict__ in,
    unsigned short* __restrict__ out, int n){
  int i = (blockIdx.x*256 + threadIdx.x)*4;
  if (i >= n) return;
  float4 v = *(const float4*)(in + i);
  ushort4 o;
  o.x = f2bf(v.x); o.y = f2bf(v.y); o.z = f2bf(v.z); o.w = f2bf(v.w);
  *(ushort4*)(out + i) = o;
}

// ---------------------------------------------------------------------------
// Generic 32x32 LDS-tiled transpose: out[C][R] = in[R][C]^T  (R1 only)
__global__ __launch_bounds__(256) void k_transpose(const float* __restrict__ in,
                                                   float* __restrict__ out, int R, int C){
  __shared__ float t[32][33];
  int bx = blockIdx.x*32, by = blockIdx.y*32;
  int x = threadIdx.x, y = threadIdx.y;   // block (32,8)
  #pragma unroll
  for (int i = 0; i < 32; i += 8){
    int r = by + y + i, c = bx + x;
    if (r < R && c < C) t[y+i][x] = in[(size_t)r*C + c];
  }
  __syncthreads();
  #pragma unroll
  for (int i = 0; i < 32; i += 8){
    int r = bx + y + i, c = by + x;       // out dims [C][R]
    if (r < C && c < R) out[(size_t)r*R + c] = t[x][y+i];
  }
}

// ---------------------------------------------------------------------------
// Gx[m][n] = sum_k se[m][k]*Wih[n][k] + bih[n] + bhh[n]   (fp32 — decision path)
__global__ __launch_bounds__(256) void k_gemm_gx(const float* __restrict__ A,
    const float* __restrict__ Bw, const float* __restrict__ bih,
    const float* __restrict__ bhh, float* __restrict__ Cout, int M, int N, int K){
  __shared__ float as[16][68];
  __shared__ float bs[16][68];
  int m0 = blockIdx.x*64, n0 = blockIdx.y*64;
  int tid = threadIdx.x;
  int mt = tid & 15, nt = tid >> 4;
  float acc[4][4] = {};
  for (int k0 = 0; k0 < K; k0 += 16){
    #pragma unroll
    for (int it = 0; it < 4; ++it){
      int idx = it*256 + tid;
      int kk = idx & 15, mm = idx >> 4;
      as[kk][mm] = A[(size_t)(m0+mm)*K + k0 + kk];
      bs[kk][mm] = Bw[(size_t)(n0+mm)*K + k0 + kk];
    }
    __syncthreads();
    #pragma unroll
    for (int kk = 0; kk < 16; ++kk){
      float a4[4], b4[4];
      #pragma unroll
      for (int i = 0; i < 4; ++i) a4[i] = as[kk][mt*4+i];
      #pragma unroll
      for (int i = 0; i < 4; ++i) b4[i] = bs[kk][nt*4+i];
      #pragma unroll
      for (int i = 0; i < 4; ++i)
        #pragma unroll
        for (int j2 = 0; j2 < 4; ++j2) acc[i][j2] += a4[i]*b4[j2];
    }
    __syncthreads();
  }
  #pragma unroll
  for (int i = 0; i < 4; ++i){
    int m = m0 + mt*4 + i;
    #pragma unroll
    for (int j2 = 0; j2 < 4; ++j2){
      int n = n0 + nt*4 + j2;
      Cout[(size_t)m*N + n] = acc[i][j2] + bih[n] + bhh[n];
    }
  }
}

// ---------------------------------------------------------------------------
// Gx [m][t][4096] -> Gxt [t][4096][m]  (for coalesced per-step gate reads)
__global__ __launch_bounds__(256) void k_gx_t(const float* __restrict__ Gx,
                                              float* __restrict__ Gxt){
  __shared__ float t2[16][257];
  int t = blockIdx.x;       // 48
  int rc = blockIdx.y;      // 16 chunks of 256 rows
  int tid = threadIdx.x;
  #pragma unroll
  for (int m = 0; m < 16; ++m)
    t2[m][tid] = Gx[((size_t)(m*48 + t))*4096 + rc*256 + tid];
  __syncthreads();
  int rl = tid >> 4, m = tid & 15;
  #pragma unroll
  for (int i = 0; i < 16; ++i){
    int r = rc*256 + i*16 + rl;
    Gxt[((size_t)t*4096 + r)*16 + m] = t2[m][i*16 + rl];
  }
}

// ---------------------------------------------------------------------------
// Persistent LSTM scan: 256 blocks x 256 threads, 1 block/CU.
// h exchanged through LLC; byte-flag barrier (single-wave poll).
// Whh held in registers, PERMUTED to match the linear LDS h layout:
//   lane kc owns k-indices {r*256 + 4*kc + j : r=0..3, j=0..3}
//   w[jj][r*4+j] = Whh[row][r*256 + 4*kc + j]
// so every LDS op is the canonical lanes-contiguous b128 pattern
// (conflict-free), and the per-step x-gate values are prefetched by all
// waves at step start (no LLC latency in the serialized tail).
__global__ __launch_bounds__(256, 1) void k_lstm_scan(
    const float* __restrict__ Whh, const float* __restrict__ Gxt,
    float* __restrict__ hs, float* __restrict__ cs,
    unsigned short* __restrict__ hs_bf, unsigned char* __restrict__ flags){
  __shared__ float smem[17408];   // 68KB: h-stage [16][1024] fp32; overlaid by reduce partials
  __shared__ float gbuf[4*64];
  __shared__ float cbuf[64];
  __shared__ int ldsok[4];
  int tid = threadIdx.x;
  int g = tid >> 6, kc = tid & 63;
  int j0 = blockIdx.x * 4;
  float w[4][16];
  #pragma unroll
  for (int jj = 0; jj < 4; ++jj){
    const float* src = Whh + (size_t)(g*1024 + j0 + jj)*1024 + kc*4;
    #pragma unroll
    for (int r = 0; r < 4; ++r){
      float4 v = *(const float4*)(src + r*256);
      w[jj][r*4+0]=v.x; w[jj][r*4+1]=v.y; w[jj][r*4+2]=v.z; w[jj][r*4+3]=v.w;
    }
  }
  if (tid < 64) cbuf[tid] = 0.f;
  for (int t = 0; t < LL; ++t){
    // prefetch this step's x-gate contribution for gate group g (read-only
    // data written before launch -> plain cached load, issued before h work)
    float gx = Gxt[((size_t)t*NG4 + g*1024 + j0 + (kc & 3))*16 + (kc >> 2)];
    float G = 0.f;
    if (t > 0){
      // batched LLC loads of h_{t-1}: 16 dwordx4 in flight, one vmcnt
      f32x4 hv[16];
      #pragma unroll
      for (int m = 0; m < 16; ++m)
        hv[m] = ld_llc4f(hs + ((size_t)(m*LL + t-1))*HH + (tid<<2));
      wait_vm0();
      #pragma unroll
      for (int m = 0; m < 16; ++m)
        *(f32x4*)&smem[m*1024 + (tid<<2)] = hv[m];   // lanes contiguous: conflict-free
      __syncthreads();
      float acc[4][16];
      #pragma unroll 4
      for (int m = 0; m < 16; ++m){
        const float* hb = &smem[m*1024 + (kc<<2)];
        float4 h0 = *(const float4*)(hb);        // canonical b128: lanes at 16B stride
        float4 h1 = *(const float4*)(hb+256);
        float4 h2 = *(const float4*)(hb+512);
        float4 h3 = *(const float4*)(hb+768);
        #pragma unroll
        for (int jj = 0; jj < 4; ++jj){
          float s = w[jj][0]*h0.x + w[jj][1]*h0.y + w[jj][2]*h0.z + w[jj][3]*h0.w
                  + w[jj][4]*h1.x + w[jj][5]*h1.y + w[jj][6]*h1.z + w[jj][7]*h1.w
                  + w[jj][8]*h2.x + w[jj][9]*h2.y + w[jj][10]*h2.z + w[jj][11]*h2.w
                  + w[jj][12]*h3.x + w[jj][13]*h3.y + w[jj][14]*h3.z + w[jj][15]*h3.w;
          acc[jj][m] = s;
        }
      }
      __syncthreads();   // h reads done; smem reused as reduce partials
      #pragma unroll
      for (int m = 0; m < 16; ++m){
        float4 v;
        v.x = acc[0][m]; v.y = acc[1][m]; v.z = acc[2][m]; v.w = acc[3][m];
        *(float4*)&smem[(size_t)(g*64 + kc)*68 + m*4] = v;
      }
      __syncthreads();
      {
        float s0=0.f,s1=0.f,s2=0.f,s3=0.f;
        #pragma unroll 4
        for (int l = 0; l < 64; l += 4){
          s0 += smem[(size_t)(g*64 + l  )*68 + kc];
          s1 += smem[(size_t)(g*64 + l+1)*68 + kc];
          s2 += smem[(size_t)(g*64 + l+2)*68 + kc];
          s3 += smem[(size_t)(g*64 + l+3)*68 + kc];
        }
        G = (s0+s1)+(s2+s3);
      }
    }
    gbuf[g*64 + kc] = G + gx;   // recurrent + input parts combined
    __syncthreads();
    if (g == 0){
      int o = kc;               // o = m*4 + jj
      int jj = o & 3, m = o >> 2;
      float gi = gbuf[0*64 + o];
      float gf = gbuf[1*64 + o];
      float gu = gbuf[2*64 + o];
      float go = gbuf[3*64 + o];
      float cp = cbuf[o];
      float c = sigf(gf)*cp + sigf(gi)*tanhf(gu);
      float h = sigf(go)*tanhf(c);
      cbuf[o] = c;
      size_t oidx = ((size_t)(m*LL + t))*HH + j0 + jj;
      st_llc(&hs[oidx], h);     // LLC write-through: visible without fences
      cs[oidx] = c;             // consumed after kernel boundary only
      hs_bf[oidx] = f2bf(h);    // consumed after kernel boundary only
    }
    if (t < LL-1)
      flagbar(flags, (unsigned)(t+1), ldsok);
  }
}

// ---------------------------------------------------------------------------
// Per-position rank-MLP score + gumbel noise (fp32 — decision path).
__global__ __launch_bounds__(128) void k_score(const float* __restrict__ R1t,
    const float* __restrict__ R2, const float* __restrict__ hs,
    const float* __restrict__ gumbel_u, float* __restrict__ score,
    float* __restrict__ snoisy){
  __shared__ float hsm[HH];
  __shared__ float red[128];
  int bt = blockIdx.x;
  int tid = threadIdx.x;
  for (int i = tid; i < HH; i += 128) hsm[i] = hs[(size_t)bt*HH + i];
  __syncthreads();
  float acc = 0.f;
  for (int k = 0; k < HH; ++k) acc += R1t[(size_t)k*RANKH + tid] * hsm[k];
  red[tid] = fmaxf(acc, 0.f) * R2[tid];
  __syncthreads();
  for (int s = 64; s > 0; s >>= 1){
    if (tid < s) red[tid] += red[tid+s];
    __syncthreads();
  }
  if (tid == 0){
    float s = red[0];
    float u = gumbel_u[bt];
    float noise = -logf(-logf(u));
    score[bt]  = s;
    snoisy[bt] = s + noise;
  }
}

// ---------------------------------------------------------------------------
// Build the tree structure for all batches. 1 block, 64 threads.
// level_count[0] <- number of levels (max height).
__global__ __launch_bounds__(64) void k_build(const float* __restrict__ score,
    const float* __restrict__ snoisy, const int* __restrict__ length,
    int* __restrict__ node_l, int* __restrict__ node_r, int* __restrict__ node_x,
    int* __restrict__ node_lvl, int* __restrict__ node_b, int* __restrict__ node_root,
    int* __restrict__ level_count, int* __restrict__ level_off, int* __restrict__ order){
  __shared__ float sc[BB*LL], sn[BB*LL];
  __shared__ int lcount[MAXLVL+1], lcur[MAXLVL+1], loff[MAXLVL+1];
  __shared__ int percnt[BB];
  int tid = threadIdx.x;
  for (int i = tid; i < BB*LL; i += 64){ sc[i] = score[i]; sn[i] = snoisy[i]; }
  for (int i = tid; i <= MAXLVL; i += 64){ lcount[i] = 0; lcur[i] = 0; }
  __syncthreads();
  if (tid < BB){
    int b = tid;
    int len = length[b];
    if (len > LL) len = LL;
    int qs[MAXN], qe[MAXN], qn[MAXN];
    int qh = 0, qt = 0, cnt = 0;
    int rootn = cnt++;
    qs[qt] = 0; qe[qt] = len; qn[qt] = rootn; qt++;
    while (qh < qt){
      int s0 = qs[qh], e0 = qe[qh], nid = qn[qh]; qh++;
      float best = sc[b*LL + s0]; int pos = s0;
      for (int t2 = s0+1; t2 < e0; ++t2){
        float v = sc[b*LL + t2];
        if (v > best){ best = v; pos = t2; }
      }
      float bestn = sn[b*LL + s0]; int js = s0;
      for (int t2 = s0+1; t2 < e0; ++t2){
        float v = sn[b*LL + t2];
        if (v > bestn){ bestn = v; js = t2; }
      }
      int gid = b*MAXN + nid;
      node_x[gid] = js;
      node_b[gid] = b;
      node_root[gid] = (nid == 0) ? 1 : 0;
      int ln = pos - s0, enc_l, enc_r;
      if (ln <= 0) enc_l = -1;
      else if (ln == 1) enc_l = 10000 + s0;
      else { int c2 = cnt++; enc_l = b*MAXN + c2; qs[qt]=s0; qe[qt]=pos; qn[qt]=c2; qt++; }
      int rn = e0 - (pos+1);
      if (rn <= 0) enc_r = -1;
      else if (rn == 1) enc_r = 10000 + (pos+1);
      else { int c2 = cnt++; enc_r = b*MAXN + c2; qs[qt]=pos+1; qe[qt]=e0; qn[qt]=c2; qt++; }
      node_l[gid] = enc_l; node_r[gid] = enc_r;
    }
    for (int i = cnt-1; i >= 0; --i){
      int gid = b*MAXN + i;
      int el = node_l[gid], er = node_r[gid];
      int llv = (el >= 0 && el < 10000) ? node_lvl[el] : 0;
      int rlv = (er >= 0 && er < 10000) ? node_lvl[er] : 0;
      node_lvl[gid] = 1 + (llv > rlv ? llv : rlv);
    }
    for (int i = 0; i < cnt; ++i) atomicAdd(&lcount[node_lvl[b*MAXN + i]], 1);
    percnt[b] = cnt;
  }
  __syncthreads();
  if (tid == 0){
    int off = 0, nlev = 0;
    for (int lv = 1; lv <= MAXLVL; ++lv){
      loff[lv] = off;
      level_off[lv] = off;
      level_count[lv] = lcount[lv];
      if (lcount[lv] > 0) nlev = lv;
      off += lcount[lv];
    }
    level_count[0] = nlev;
  }
  __syncthreads();
  if (tid < BB){
    int b = tid;
    int cnt = percnt[b];
    for (int i = 0; i < cnt; ++i){
      int gid = b*MAXN + i;
      int lv = node_lvl[gid];
      int p = atomicAdd(&lcur[lv], 1);
      order[loff[lv] + p] = gid;
    }
  }
}

// ---------------------------------------------------------------------------
// Persistent tree composition, byte-flag barriers, NO wb/inv.
// Wc is LDS-RESIDENT: each of the 256 blocks owns 24 Wc rows (144KB, loaded
// once, XOR-swizzled). Per level every block computes its 24 gate columns for
// ALL nodes of the level; A-frags are L2-broadcast reads, B from LDS.
// Coherence protocol:
//  - gates: LLC stores (A) -> LLC loads (B)
//  - nodeH_bf / nodeC: LLC stores (B) -> normal cached first-reads later
//  - Wc_bf / hs_bf / order / node_*: read-only, cached.
__global__ __launch_bounds__(256, 1) void k_tree(
    const unsigned short* __restrict__ Wc_bf,
    const unsigned short* __restrict__ hs_bf,
    unsigned short* __restrict__ nodeH_bf,
    const unsigned short* __restrict__ zrow,
    const float* __restrict__ bc, const float* __restrict__ cs,
    float* __restrict__ nodeC,
    const int* __restrict__ node_l, const int* __restrict__ node_r,
    const int* __restrict__ node_x, const int* __restrict__ node_b,
    const int* __restrict__ node_root, const int* __restrict__ level_count,
    const int* __restrict__ level_off, const int* __restrict__ order,
    float* __restrict__ gates, float* __restrict__ out,
    unsigned char* __restrict__ flags){
  __shared__ __align__(16) unsigned char wlds[24*6144];   // 144KB Wc slice
  __shared__ int ldsok[4];
  int tid = threadIdx.x;
  int lane = tid & 63;
  int wave = tid >> 6;
  int fr = lane & 15;          // fragment row (A: node slot, B: Wc row)
  int fkq = lane >> 4;         // k-quarter 0..3
  int fk  = fkq * 8;           // element offset within 32-elem k-chunk
  int fkb = fkq * 16;          // byte offset
  int swz = (fr & 7) << 4;     // XOR swizzle (G4: row-major stride-6144B tile)
  int base0 = fr * 6144;               // n-tile 0: rows 0..15
  int base1 = (16 + (fr & 7)) * 6144;  // n-tile 1: rows 16..23 (dup for fr>=8)
  int rg24 = blockIdx.x * 24;  // this block's 24 Wc rows / gate columns

  // ---- one-time: stage 24 Wc rows into LDS, swizzled ----
  for (int i = tid; i < 24*384; i += 256){
    int row = i / 384;
    int ch  = i - row*384;     // 16B chunk within row
    uint4 v = *(const uint4*)(Wc_bf + (size_t)(rg24 + row)*K3H + ch*8);
    *(uint4*)(wlds + row*6144 + ((ch*16) ^ ((row & 7) << 4))) = v;
  }
  __syncthreads();

  int nlev = level_count[0];
  unsigned ph = 0;
  for (int lvl = 1; lvl <= nlev; ++lvl){
    int n = level_count[lvl];
    int loffv = level_off[lvl];
    // ---- Phase A: all nodes x this block's 24 Wc rows, B from LDS ----
    int mtiles = (n + 15) >> 4;
    for (int mt = wave; mt < mtiles; mt += 4){
      int slot = mt*16 + fr;
      const unsigned short *pa0, *pa1, *pa2;
      if (slot < n){
        int gid = order[loffv + slot];
        int b = node_b[gid];
        int el = node_l[gid], er = node_r[gid], xt = node_x[gid];
        pa0 = (el < 0) ? zrow : (el >= 10000 ? hs_bf + (size_t)(b*LL + (el-10000))*HH
                                             : nodeH_bf + (size_t)el*HH);
        pa1 = (er < 0) ? zrow : (er >= 10000 ? hs_bf + (size_t)(b*LL + (er-10000))*HH
                                             : nodeH_bf + (size_t)er*HH);
        pa2 = hs_bf + (size_t)(b*LL + xt)*HH;
      } else { pa0 = zrow; pa1 = zrow; pa2 = zrow; }
      const unsigned short* pa[3] = {pa0, pa1, pa2};
      f32x4 acc0 = {0.f,0.f,0.f,0.f};
      f32x4 acc1 = {0.f,0.f,0.f,0.f};
      #pragma unroll
      for (int part = 0; part < 3; ++part){
        const unsigned short* ap = pa[part] + fk;
        #pragma unroll 8
        for (int kcc = 0; kcc < 1024; kcc += 32){
          bf16x8 a = *(const bf16x8*)(ap + kcc);
          int xb = part*2048 + kcc*2 + fkb;
          bf16x8 b0 = *(const bf16x8*)(wlds + base0 + (xb ^ swz));
          bf16x8 b1 = *(const bf16x8*)(wlds + base1 + (xb ^ swz));
          acc0 = __builtin_amdgcn_mfma_f32_16x16x32_bf16(a, b0, acc0, 0, 0, 0);
          acc1 = __builtin_amdgcn_mfma_f32_16x16x32_bf16(a, b1, acc1, 0, 0, 0);
        }
      }
      int m0 = mt*16 + fkq*4;
      #pragma unroll
      for (int r = 0; r < 4; ++r){
        int m = m0 + r;
        if (m < n){
          st_llc(&gates[(size_t)m*NG6 + rg24 + fr], acc0[r]);
          if (fr < 8)
            st_llc(&gates[(size_t)m*NG6 + rg24 + 16 + fr], acc1[r]);
        }
      }
    }
    ph++;
    flagbar(flags, ph, ldsok);
    // ---- Phase B: epilogue ----
    int items = n * 4;
    for (int it = blockIdx.x; it < items; it += 256){
      int ns = it >> 2;
      int j = (it & 3)*256 + tid;
      int gid = order[loffv + ns];
      int b = node_b[gid];
      int el = node_l[gid], er = node_r[gid], xt = node_x[gid];
      float gg[6];
      #pragma unroll
      for (int q = 0; q < 6; ++q)
        gg[q] = bc[q*HH + j] + ld_llc(&gates[(size_t)ns*NG6 + q*HH + j]);
      float lc = (el < 0) ? 0.f : (el >= 10000 ? cs[(size_t)(b*LL + (el-10000))*HH + j]
                                               : nodeC[(size_t)el*HH + j]);
      float rc = (er < 0) ? 0.f : (er >= 10000 ? cs[(size_t)(b*LL + (er-10000))*HH + j]
                                               : nodeC[(size_t)er*HH + j]);
      float xc = cs[(size_t)(b*LL + xt)*HH + j];
      float c = sigf(gg[0])*tanhf(gg[4]) + sigf(gg[1])*lc + sigf(gg[2])*rc + sigf(gg[3])*xc;
      float h = sigf(gg[5])*tanhf(c);
      st_llc_u16(&nodeH_bf[(size_t)gid*HH + j], (unsigned)f2bf(h));
      st_llc(&nodeC[(size_t)gid*HH + j], c);
      if (node_root[gid]){
        out[(size_t)b*HH + j] = h;
        out[(size_t)BB*HH + (size_t)b*HH + j] = c;
      }
    }
    if (lvl < nlev){
      ph++;
      flagbar(flags, ph, ldsok);
    }
  }
}

// ---------------------------------------------------------------------------
extern "C" void kernel_launch(void* const* d_in, const int* in_sizes, int n_in,
                              void* d_out, int out_size, void* d_ws, size_t ws_size,
                              hipStream_t stream){
  const float* se  = (const float*)d_in[0];
  const float* gu  = (const float*)d_in[1];
  const float* Wih = (const float*)d_in[2];
  const float* Whh = (const float*)d_in[3];
  const float* bih = (const float*)d_in[4];
  const float* bhh = (const float*)d_in[5];
  const float* R1  = (const float*)d_in[6];
  const float* R2  = (const float*)d_in[7];
  const float* Wc  = (const float*)d_in[8];
  const float* bc  = (const float*)d_in[9];
  const int*   len = (const int*)d_in[10];
  float* out = (float*)d_out;                 // [2,16,1024] fp32

  float* ws = (float*)d_ws;
  size_t off = 0;
  float* R1t   = ws + off; off += (size_t)HH*RANKH;
  float* Gx    = ws + off; off += (size_t)BB*LL*NG4;     // [m][t][4096]
  float* Gxt   = ws + off; off += (size_t)BB*LL*NG4;     // [t][4096][m]
  float* hs    = ws + off; off += (size_t)BB*LL*HH;
  float* cs    = ws + off; off += (size_t)BB*LL*HH;
  float* nodeC = ws + off; off += (size_t)TOTN*HH;
  float* gates = ws + off; off += (size_t)MAXNPL*NG6;
  unsigned short* Wc_bf    = (unsigned short*)(ws + off); off += (size_t)NG6*K3H/2;
  unsigned short* hs_bf    = (unsigned short*)(ws + off); off += (size_t)BB*LL*HH/2;
  unsigned short* nodeH_bf = (unsigned short*)(ws + off); off += (size_t)TOTN*HH/2 + 512;
  unsigned short* zrow     = (unsigned short*)(ws + off); off += 512;  // 1024 zero bf16
  float* score = ws + off; off += 1024;
  float* snoi  = ws + off; off += 1024;
  unsigned* flags = (unsigned*)(ws + off); off += 512;   // byte flags: scan @0, tree @ +1024B
  int* ib = (int*)(ws + off);
  int* node_l    = ib; ib += 768;
  int* node_r    = ib; ib += 768;
  int* node_x    = ib; ib += 768;
  int* node_lvl  = ib; ib += 768;
  int* node_b    = ib; ib += 768;
  int* node_root = ib; ib += 768;
  int* level_count = ib; ib += 64;
  int* level_off   = ib; ib += 64;
  int* order       = ib; ib += 768;

  // 0. zero flag arrays + dummy zero row (ws poisoned every launch)
  k_init<<<1, 256, 0, stream>>>(flags, zrow);
  // 1. R1 transpose + Wc bf16 conversion
  k_transpose<<<dim3(32, 4), dim3(32, 8), 0, stream>>>(R1, R1t, RANKH, HH);
  k_cvt_bf16<<<(NG6*K3H)/1024, 256, 0, stream>>>(Wc, Wc_bf, NG6*K3H);
  // 2. input-side gate GEMM (+ both biases), then transpose for the scan
  k_gemm_gx<<<dim3(12, 64), 256, 0, stream>>>(se, Wih, bih, bhh, Gx, BB*LL, NG4, HH);
  k_gx_t<<<dim3(48, 16), 256, 0, stream>>>(Gx, Gxt);
  // 3. persistent recurrent LSTM scan (48 steps, byte-flag barriers)
  k_lstm_scan<<<256, 256, 0, stream>>>(Whh, Gxt, hs, cs, hs_bf,
                                       (unsigned char*)flags);
  // 4. per-position scores + gumbel noise (fp32)
  k_score<<<BB*LL, 128, 0, stream>>>(R1t, R2, hs, gu, score, snoi);
  // 5. tree structure
  k_build<<<1, 64, 0, stream>>>(score, snoi, len, node_l, node_r, node_x,
                                node_lvl, node_b, node_root,
                                level_count, level_off, order);
  // 6. persistent level-by-level nary composition (LDS-resident Wc)
  k_tree<<<256, 256, 0, stream>>>(Wc_bf, hs_bf, nodeH_bf, zrow, bc, cs, nodeC,
                                  node_l, node_r, node_x, node_b, node_root,
                                  level_count, level_off, order,
                                  gates, out, (unsigned char*)(flags + 256));
}

// Round 3
// 1444.716 us; speedup vs baseline: 1.4341x; 1.0003x over previous
//
#include <hip/hip_runtime.h>
#include <math.h>

#define BB 16
#define LL 48
#define HH 1024
#define NG4 4096      // 4*H
#define NG6 6144      // 6*H
#define K3H 3072      // 3*H
#define RANKH 128
#define MAXN 47       // max nodes per batch (len-1 <= 47)
#define TOTN (BB*MAXN)
#define MAXLVL 48
#define MAXNPL 384    // max nodes in one level

typedef __attribute__((ext_vector_type(8))) short bf16x8;
typedef __attribute__((ext_vector_type(4))) float f32x4;

__device__ __forceinline__ float sigf(float x){ return 1.f/(1.f + expf(-x)); }

__device__ __forceinline__ unsigned short f2bf(float f){
  union { float f; unsigned u; } v; v.f = f;
  unsigned r = v.u + 0x7fff + ((v.u >> 16) & 1);
  return (unsigned short)(r >> 16);
}

// ---- LLC-coherent ops (device coherence point; bypass L1/L2, no allocate) ----
__device__ __forceinline__ void st_llc(float* p, float v){
  __hip_atomic_store(p, v, __ATOMIC_RELAXED, __HIP_MEMORY_SCOPE_AGENT);
}
__device__ __forceinline__ float ld_llc(const float* p){
  return __hip_atomic_load(p, __ATOMIC_RELAXED, __HIP_MEMORY_SCOPE_AGENT);
}
__device__ __forceinline__ void st_llc_u16(unsigned short* p, unsigned v){
  asm volatile("global_store_short %0, %1, off sc0 sc1" :: "v"(p), "v"(v) : "memory");
}
__device__ __forceinline__ void st_llc_u8(unsigned char* p, unsigned v){
  asm volatile("global_store_byte %0, %1, off sc0 sc1" :: "v"(p), "v"(v) : "memory");
}
__device__ __forceinline__ void wait_vm0(){
  asm volatile("s_waitcnt vmcnt(0)" ::: "memory");
}

// Distributed-flag grid barrier: NO atomic RMW, NO writeback, NO invalidate.
// BYTE flags (256B = few cache lines); only wave 0 polls (one dword load per
// lane covers 4 block-flags -> all 256 flags in ONE wave-load), result is
// broadcast to the other waves through LDS. Each block stores its flag byte
// after vmcnt(0) (its LLC stores are ack'd). Data crossing the barrier must
// use LLC ops (st_llc*) or be first-read-after-write.
// Phase values must stay < 256 (max used here is ~94).
// flags MUST be zeroed every launch (workspace re-poisoned to 0xAA).
__device__ __forceinline__ void flagbar(unsigned char* flags, unsigned p, int* ldsok){
  wait_vm0();
  __syncthreads();
  int tid = threadIdx.x;
  if (tid == 0)
    st_llc_u8(&flags[blockIdx.x], p);
  for (;;){
    if (tid < 64){
      unsigned v;
      asm volatile("global_load_dword %0, %1, off sc0 sc1"
                   : "=v"(v) : "v"((const unsigned*)flags + tid));
      wait_vm0();
      int ok = (int)(((v      ) & 255u) >= p) & (int)(((v >>  8) & 255u) >= p)
             & (int)(((v >> 16) & 255u) >= p) & (int)(((v >> 24)       ) >= p);
      int all64 = __all(ok);
      if (tid == 0) ldsok[0] = all64;
    }
    __syncthreads();
    if (ldsok[0]) break;
    __builtin_amdgcn_s_sleep(1);
    __syncthreads();
  }
}

// ---------------------------------------------------------------------------
// Zero flag arrays (bytes [0..255]=scan at uint ofs 0, [1024..1279]=tree at
// uint ofs 256) + the zero dummy row.
__global__ __launch_bounds__(256) void k_init(unsigned* flags, unsigned short* zrow){
  int tid = threadIdx.x;
  flags[tid] = 0u;
  flags[256 + tid] = 0u;
  for (int i = tid; i < 1024; i += 256) zrow[i] = 0;
}

// ---------------------------------------------------------------------------
// fp32 -> bf16 (RNE), vectorized. n multiple of 1024.
__global__ __launch_bounds__(256) void k_cvt_bf16(const float* __restrict__ in,
    unsigned short* __restrict__ out, int n){
  int i = (blockIdx.x*256 + threadIdx.x)*4;
  if (i >= n) return;
  float4 v = *(const float4*)(in + i);
  ushort4 o;
  o.x = f2bf(v.x); o.y = f2bf(v.y); o.z = f2bf(v.z); o.w = f2bf(v.w);
  *(ushort4*)(out + i) = o;
}

// ---------------------------------------------------------------------------
// Generic 32x32 LDS-tiled transpose: out[C][R] = in[R][C]^T  (R1 only)
__global__ __launch_bounds__(256) void k_transpose(const float* __restrict__ in,
                                                   float* __restrict__ out, int R, int C){
  __shared__ float t[32][33];
  int bx = blockIdx.x*32, by = blockIdx.y*32;
  int x = threadIdx.x, y = threadIdx.y;   // block (32,8)
  #pragma unroll
  for (int i = 0; i < 32; i += 8){
    int r = by + y + i, c = bx + x;
    if (r < R && c < C) t[y+i][x] = in[(size_t)r*C + c];
  }
  __syncthreads();
  #pragma unroll
  for (int i = 0; i < 32; i += 8){
    int r = bx + y + i, c = by + x;       // out dims [C][R]
    if (r < C && c < R) out[(size_t)r*R + c] = t[x][y+i];
  }
}

// ---------------------------------------------------------------------------
// Gx[m][n] = sum_k se[m][k]*Wih[n][k] + bih[n] + bhh[n]   (fp32 — decision path)
__global__ __launch_bounds__(256) void k_gemm_gx(const float* __restrict__ A,
    const float* __restrict__ Bw, const float* __restrict__ bih,
    const float* __restrict__ bhh, float* __restrict__ Cout, int M, int N, int K){
  __shared__ float as[16][68];
  __shared__ float bs[16][68];
  int m0 = blockIdx.x*64, n0 = blockIdx.y*64;
  int tid = threadIdx.x;
  int mt = tid & 15, nt = tid >> 4;
  float acc[4][4] = {};
  for (int k0 = 0; k0 < K; k0 += 16){
    #pragma unroll
    for (int it = 0; it < 4; ++it){
      int idx = it*256 + tid;
      int kk = idx & 15, mm = idx >> 4;
      as[kk][mm] = A[(size_t)(m0+mm)*K + k0 + kk];
      bs[kk][mm] = Bw[(size_t)(n0+mm)*K + k0 + kk];
    }
    __syncthreads();
    #pragma unroll
    for (int kk = 0; kk < 16; ++kk){
      float a4[4], b4[4];
      #pragma unroll
      for (int i = 0; i < 4; ++i) a4[i] = as[kk][mt*4+i];
      #pragma unroll
      for (int i = 0; i < 4; ++i) b4[i] = bs[kk][nt*4+i];
      #pragma unroll
      for (int i = 0; i < 4; ++i)
        #pragma unroll
        for (int j2 = 0; j2 < 4; ++j2) acc[i][j2] += a4[i]*b4[j2];
    }
    __syncthreads();
  }
  #pragma unroll
  for (int i = 0; i < 4; ++i){
    int m = m0 + mt*4 + i;
    #pragma unroll
    for (int j2 = 0; j2 < 4; ++j2){
      int n = n0 + nt*4 + j2;
      Cout[(size_t)m*N + n] = acc[i][j2] + bih[n] + bhh[n];
    }
  }
}

// ---------------------------------------------------------------------------
// Gx [m][t][4096] -> Gxt [t][4096][m]  (for coalesced per-step gate reads)
__global__ __launch_bounds__(256) void k_gx_t(const float* __restrict__ Gx,
                                              float* __restrict__ Gxt){
  __shared__ float t2[16][257];
  int t = blockIdx.x;       // 48
  int rc = blockIdx.y;      // 16 chunks of 256 rows
  int tid = threadIdx.x;
  #pragma unroll
  for (int m = 0; m < 16; ++m)
    t2[m][tid] = Gx[((size_t)(m*48 + t))*4096 + rc*256 + tid];
  __syncthreads();
  int rl = tid >> 4, m = tid & 15;
  #pragma unroll
  for (int i = 0; i < 16; ++i){
    int r = rc*256 + i*16 + rl;
    Gxt[((size_t)t*4096 + r)*16 + m] = t2[m][i*16 + rl];
  }
}

// ---------------------------------------------------------------------------
// Persistent LSTM scan: 256 blocks x 256 threads, 1 block/CU.
// h writes go through LLC (st_llc); h READS are PLAIN CACHED loads:
// each 4KB h-slice is written exactly once (bypassing all L2s) and
// first-read here at addresses no L1/L2 has ever held (slices are
// 4KB-aligned; 128B lines never straddle slices; per-dispatch acquire
// invalidates caches between launches) -> every miss fetches the fresh
// LLC line, and the 32 blocks of an XCD then share it in L2 instead of
// 256 blocks each hitting the LLC's uncached path (16MB/step -> ~0.5MB).
// Whh held in registers, PERMUTED to match the linear LDS h layout:
//   lane kc owns k-indices {r*256 + 4*kc + j : r=0..3, j=0..3}
//   w[jj][r*4+j] = Whh[row][r*256 + 4*kc + j]
// so every LDS op is the canonical lanes-contiguous b128 pattern.
__global__ __launch_bounds__(256, 1) void k_lstm_scan(
    const float* __restrict__ Whh, const float* __restrict__ Gxt,
    float* __restrict__ hs, float* __restrict__ cs,
    unsigned short* __restrict__ hs_bf, unsigned char* __restrict__ flags){
  __shared__ float smem[17408];   // 68KB: h-stage [16][1024] fp32; overlaid by reduce partials
  __shared__ float gbuf[4*64];
  __shared__ float cbuf[64];
  __shared__ int ldsok[4];
  int tid = threadIdx.x;
  int g = tid >> 6, kc = tid & 63;
  int j0 = blockIdx.x * 4;
  float w[4][16];
  #pragma unroll
  for (int jj = 0; jj < 4; ++jj){
    const float* src = Whh + (size_t)(g*1024 + j0 + jj)*1024 + kc*4;
    #pragma unroll
    for (int r = 0; r < 4; ++r){
      float4 v = *(const float4*)(src + r*256);
      w[jj][r*4+0]=v.x; w[jj][r*4+1]=v.y; w[jj][r*4+2]=v.z; w[jj][r*4+3]=v.w;
    }
  }
  if (tid < 64) cbuf[tid] = 0.f;
  for (int t = 0; t < LL; ++t){
    // prefetch this step's x-gate contribution for gate group g (read-only
    // data written before launch -> plain cached load, issued before h work)
    float gx = Gxt[((size_t)t*NG4 + g*1024 + j0 + (kc & 3))*16 + (kc >> 2)];
    float G = 0.f;
    if (t > 0){
      // h_{t-1}: plain cached dwordx4 loads (first-read-after-write, L2-shared)
      f32x4 hv[16];
      #pragma unroll
      for (int m = 0; m < 16; ++m)
        hv[m] = *(const f32x4*)(hs + ((size_t)(m*LL + t-1))*HH + (tid<<2));
      #pragma unroll
      for (int m = 0; m < 16; ++m)
        *(f32x4*)&smem[m*1024 + (tid<<2)] = hv[m];   // lanes contiguous: conflict-free
      __syncthreads();
      float acc[4][16];
      #pragma unroll 4
      for (int m = 0; m < 16; ++m){
        const float* hb = &smem[m*1024 + (kc<<2)];
        float4 h0 = *(const float4*)(hb);        // canonical b128: lanes at 16B stride
        float4 h1 = *(const float4*)(hb+256);
        float4 h2 = *(const float4*)(hb+512);
        float4 h3 = *(const float4*)(hb+768);
        #pragma unroll
        for (int jj = 0; jj < 4; ++jj){
          float s = w[jj][0]*h0.x + w[jj][1]*h0.y + w[jj][2]*h0.z + w[jj][3]*h0.w
                  + w[jj][4]*h1.x + w[jj][5]*h1.y + w[jj][6]*h1.z + w[jj][7]*h1.w
                  + w[jj][8]*h2.x + w[jj][9]*h2.y + w[jj][10]*h2.z + w[jj][11]*h2.w
                  + w[jj][12]*h3.x + w[jj][13]*h3.y + w[jj][14]*h3.z + w[jj][15]*h3.w;
          acc[jj][m] = s;
        }
      }
      __syncthreads();   // h reads done; smem reused as reduce partials
      #pragma unroll
      for (int m = 0; m < 16; ++m){
        float4 v;
        v.x = acc[0][m]; v.y = acc[1][m]; v.z = acc[2][m]; v.w = acc[3][m];
        *(float4*)&smem[(size_t)(g*64 + kc)*68 + m*4] = v;
      }
      __syncthreads();
      {
        float s0=0.f,s1=0.f,s2=0.f,s3=0.f;
        #pragma unroll 4
        for (int l = 0; l < 64; l += 4){
          s0 += smem[(size_t)(g*64 + l  )*68 + kc];
          s1 += smem[(size_t)(g*64 + l+1)*68 + kc];
          s2 += smem[(size_t)(g*64 + l+2)*68 + kc];
          s3 += smem[(size_t)(g*64 + l+3)*68 + kc];
        }
        G = (s0+s1)+(s2+s3);
      }
    }
    gbuf[g*64 + kc] = G + gx;   // recurrent + input parts combined
    __syncthreads();
    if (g == 0){
      int o = kc;               // o = m*4 + jj
      int jj = o & 3, m = o >> 2;
      float gi = gbuf[0*64 + o];
      float gf = gbuf[1*64 + o];
      float gu = gbuf[2*64 + o];
      float go = gbuf[3*64 + o];
      float cp = cbuf[o];
      float c = sigf(gf)*cp + sigf(gi)*tanhf(gu);
      float h = sigf(go)*tanhf(c);
      cbuf[o] = c;
      size_t oidx = ((size_t)(m*LL + t))*HH + j0 + jj;
      st_llc(&hs[oidx], h);     // LLC write-through: visible without fences
      cs[oidx] = c;             // consumed after kernel boundary only
      hs_bf[oidx] = f2bf(h);    // consumed after kernel boundary only
    }
    if (t < LL-1)
      flagbar(flags, (unsigned)(t+1), ldsok);
  }
}

// ---------------------------------------------------------------------------
// Per-position rank-MLP score + gumbel noise (fp32 — decision path).
__global__ __launch_bounds__(128) void k_score(const float* __restrict__ R1t,
    const float* __restrict__ R2, const float* __restrict__ hs,
    const float* __restrict__ gumbel_u, float* __restrict__ score,
    float* __restrict__ snoisy){
  __shared__ float hsm[HH];
  __shared__ float red[128];
  int bt = blockIdx.x;
  int tid = threadIdx.x;
  for (int i = tid; i < HH; i += 128) hsm[i] = hs[(size_t)bt*HH + i];
  __syncthreads();
  float acc = 0.f;
  for (int k = 0; k < HH; ++k) acc += R1t[(size_t)k*RANKH + tid] * hsm[k];
  red[tid] = fmaxf(acc, 0.f) * R2[tid];
  __syncthreads();
  for (int s = 64; s > 0; s >>= 1){
    if (tid < s) red[tid] += red[tid+s];
    __syncthreads();
  }
  if (tid == 0){
    float s = red[0];
    float u = gumbel_u[bt];
    float noise = -logf(-logf(u));
    score[bt]  = s;
    snoisy[bt] = s + noise;
  }
}

// ---------------------------------------------------------------------------
// Build the tree structure for all batches. 1 block, 64 threads.
// level_count[0] <- number of levels (max height).
__global__ __launch_bounds__(64) void k_build(const float* __restrict__ score,
    const float* __restrict__ snoisy, const int* __restrict__ length,
    int* __restrict__ node_l, int* __restrict__ node_r, int* __restrict__ node_x,
    int* __restrict__ node_lvl, int* __restrict__ node_b, int* __restrict__ node_root,
    int* __restrict__ level_count, int* __restrict__ level_off, int* __restrict__ order){
  __shared__ float sc[BB*LL], sn[BB*LL];
  __shared__ int lcount[MAXLVL+1], lcur[MAXLVL+1], loff[MAXLVL+1];
  __shared__ int percnt[BB];
  int tid = threadIdx.x;
  for (int i = tid; i < BB*LL; i += 64){ sc[i] = score[i]; sn[i] = snoisy[i]; }
  for (int i = tid; i <= MAXLVL; i += 64){ lcount[i] = 0; lcur[i] = 0; }
  __syncthreads();
  if (tid < BB){
    int b = tid;
    int len = length[b];
    if (len > LL) len = LL;
    int qs[MAXN], qe[MAXN], qn[MAXN];
    int qh = 0, qt = 0, cnt = 0;
    int rootn = cnt++;
    qs[qt] = 0; qe[qt] = len; qn[qt] = rootn; qt++;
    while (qh < qt){
      int s0 = qs[qh], e0 = qe[qh], nid = qn[qh]; qh++;
      float best = sc[b*LL + s0]; int pos = s0;
      for (int t2 = s0+1; t2 < e0; ++t2){
        float v = sc[b*LL + t2];
        if (v > best){ best = v; pos = t2; }
      }
      float bestn = sn[b*LL + s0]; int js = s0;
      for (int t2 = s0+1; t2 < e0; ++t2){
        float v = sn[b*LL + t2];
        if (v > bestn){ bestn = v; js = t2; }
      }
      int gid = b*MAXN + nid;
      node_x[gid] = js;
      node_b[gid] = b;
      node_root[gid] = (nid == 0) ? 1 : 0;
      int ln = pos - s0, enc_l, enc_r;
      if (ln <= 0) enc_l = -1;
      else if (ln == 1) enc_l = 10000 + s0;
      else { int c2 = cnt++; enc_l = b*MAXN + c2; qs[qt]=s0; qe[qt]=pos; qn[qt]=c2; qt++; }
      int rn = e0 - (pos+1);
      if (rn <= 0) enc_r = -1;
      else if (rn == 1) enc_r = 10000 + (pos+1);
      else { int c2 = cnt++; enc_r = b*MAXN + c2; qs[qt]=pos+1; qe[qt]=e0; qn[qt]=c2; qt++; }
      node_l[gid] = enc_l; node_r[gid] = enc_r;
    }
    for (int i = cnt-1; i >= 0; --i){
      int gid = b*MAXN + i;
      int el = node_l[gid], er = node_r[gid];
      int llv = (el >= 0 && el < 10000) ? node_lvl[el] : 0;
      int rlv = (er >= 0 && er < 10000) ? node_lvl[er] : 0;
      node_lvl[gid] = 1 + (llv > rlv ? llv : rlv);
    }
    for (int i = 0; i < cnt; ++i) atomicAdd(&lcount[node_lvl[b*MAXN + i]], 1);
    percnt[b] = cnt;
  }
  __syncthreads();
  if (tid == 0){
    int off = 0, nlev = 0;
    for (int lv = 1; lv <= MAXLVL; ++lv){
      loff[lv] = off;
      level_off[lv] = off;
      level_count[lv] = lcount[lv];
      if (lcount[lv] > 0) nlev = lv;
      off += lcount[lv];
    }
    level_count[0] = nlev;
  }
  __syncthreads();
  if (tid < BB){
    int b = tid;
    int cnt = percnt[b];
    for (int i = 0; i < cnt; ++i){
      int gid = b*MAXN + i;
      int lv = node_lvl[gid];
      int p = atomicAdd(&lcur[lv], 1);
      order[loff[lv] + p] = gid;
    }
  }
}

// ---------------------------------------------------------------------------
// Persistent tree composition, byte-flag barriers, NO wb/inv.
// Wc is LDS-RESIDENT: each of the 256 blocks owns 24 Wc rows (144KB, loaded
// once, XOR-swizzled). Per level every block computes its 24 gate columns for
// ALL nodes of the level; A-frags are L2-broadcast reads, B from LDS.
// Coherence protocol:
//  - gates: LLC stores (A) -> LLC loads (B)
//  - nodeH_bf / nodeC: LLC stores (B) -> normal cached first-reads later
//  - Wc_bf / hs_bf / order / node_*: read-only, cached.
__global__ __launch_bounds__(256, 1) void k_tree(
    const unsigned short* __restrict__ Wc_bf,
    const unsigned short* __restrict__ hs_bf,
    unsigned short* __restrict__ nodeH_bf,
    const unsigned short* __restrict__ zrow,
    const float* __restrict__ bc, const float* __restrict__ cs,
    float* __restrict__ nodeC,
    const int* __restrict__ node_l, const int* __restrict__ node_r,
    const int* __restrict__ node_x, const int* __restrict__ node_b,
    const int* __restrict__ node_root, const int* __restrict__ level_count,
    const int* __restrict__ level_off, const int* __restrict__ order,
    float* __restrict__ gates, float* __restrict__ out,
    unsigned char* __restrict__ flags){
  __shared__ __align__(16) unsigned char wlds[24*6144];   // 144KB Wc slice
  __shared__ int ldsok[4];
  int tid = threadIdx.x;
  int lane = tid & 63;
  int wave = tid >> 6;
  int fr = lane & 15;          // fragment row (A: node slot, B: Wc row)
  int fkq = lane >> 4;         // k-quarter 0..3
  int fk  = fkq * 8;           // element offset within 32-elem k-chunk
  int fkb = fkq * 16;          // byte offset
  int swz = (fr & 7) << 4;     // XOR swizzle (G4: row-major stride-6144B tile)
  int base0 = fr * 6144;               // n-tile 0: rows 0..15
  int base1 = (16 + (fr & 7)) * 6144;  // n-tile 1: rows 16..23 (dup for fr>=8)
  int rg24 = blockIdx.x * 24;  // this block's 24 Wc rows / gate columns

  // ---- one-time: stage 24 Wc rows into LDS, swizzled ----
  for (int i = tid; i < 24*384; i += 256){
    int row = i / 384;
    int ch  = i - row*384;     // 16B chunk within row
    uint4 v = *(const uint4*)(Wc_bf + (size_t)(rg24 + row)*K3H + ch*8);
    *(uint4*)(wlds + row*6144 + ((ch*16) ^ ((row & 7) << 4))) = v;
  }
  __syncthreads();

  int nlev = level_count[0];
  unsigned ph = 0;
  for (int lvl = 1; lvl <= nlev; ++lvl){
    int n = level_count[lvl];
    int loffv = level_off[lvl];
    // ---- Phase A: all nodes x this block's 24 Wc rows, B from LDS ----
    int mtiles = (n + 15) >> 4;
    for (int mt = wave; mt < mtiles; mt += 4){
      int slot = mt*16 + fr;
      const unsigned short *pa0, *pa1, *pa2;
      if (slot < n){
        int gid = order[loffv + slot];
        int b = node_b[gid];
        int el = node_l[gid], er = node_r[gid], xt = node_x[gid];
        pa0 = (el < 0) ? zrow : (el >= 10000 ? hs_bf + (size_t)(b*LL + (el-10000))*HH
                                             : nodeH_bf + (size_t)el*HH);
        pa1 = (er < 0) ? zrow : (er >= 10000 ? hs_bf + (size_t)(b*LL + (er-10000))*HH
                                             : nodeH_bf + (size_t)er*HH);
        pa2 = hs_bf + (size_t)(b*LL + xt)*HH;
      } else { pa0 = zrow; pa1 = zrow; pa2 = zrow; }
      const unsigned short* pa[3] = {pa0, pa1, pa2};
      f32x4 acc0 = {0.f,0.f,0.f,0.f};
      f32x4 acc1 = {0.f,0.f,0.f,0.f};
      #pragma unroll
      for (int part = 0; part < 3; ++part){
        const unsigned short* ap = pa[part] + fk;
        #pragma unroll 8
        for (int kcc = 0; kcc < 1024; kcc += 32){
          bf16x8 a = *(const bf16x8*)(ap + kcc);
          int xb = part*2048 + kcc*2 + fkb;
          bf16x8 b0 = *(const bf16x8*)(wlds + base0 + (xb ^ swz));
          bf16x8 b1 = *(const bf16x8*)(wlds + base1 + (xb ^ swz));
          acc0 = __builtin_amdgcn_mfma_f32_16x16x32_bf16(a, b0, acc0, 0, 0, 0);
          acc1 = __builtin_amdgcn_mfma_f32_16x16x32_bf16(a, b1, acc1, 0, 0, 0);
        }
      }
      int m0 = mt*16 + fkq*4;
      #pragma unroll
      for (int r = 0; r < 4; ++r){
        int m = m0 + r;
        if (m < n){
          st_llc(&gates[(size_t)m*NG6 + rg24 + fr], acc0[r]);
          if (fr < 8)
            st_llc(&gates[(size_t)m*NG6 + rg24 + 16 + fr], acc1[r]);
        }
      }
    }
    ph++;
    flagbar(flags, ph, ldsok);
    // ---- Phase B: epilogue ----
    int items = n * 4;
    for (int it = blockIdx.x; it < items; it += 256){
      int ns = it >> 2;
      int j = (it & 3)*256 + tid;
      int gid = order[loffv + ns];
      int b = node_b[gid];
      int el = node_l[gid], er = node_r[gid], xt = node_x[gid];
      float gg[6];
      #pragma unroll
      for (int q = 0; q < 6; ++q)
        gg[q] = bc[q*HH + j] + ld_llc(&gates[(size_t)ns*NG6 + q*HH + j]);
      float lc = (el < 0) ? 0.f : (el >= 10000 ? cs[(size_t)(b*LL + (el-10000))*HH + j]
                                               : nodeC[(size_t)el*HH + j]);
      float rc = (er < 0) ? 0.f : (er >= 10000 ? cs[(size_t)(b*LL + (er-10000))*HH + j]
                                               : nodeC[(size_t)er*HH + j]);
      float xc = cs[(size_t)(b*LL + xt)*HH + j];
      float c = sigf(gg[0])*tanhf(gg[4]) + sigf(gg[1])*lc + sigf(gg[2])*rc + sigf(gg[3])*xc;
      float h = sigf(gg[5])*tanhf(c);
      st_llc_u16(&nodeH_bf[(size_t)gid*HH + j], (unsigned)f2bf(h));
      st_llc(&nodeC[(size_t)gid*HH + j], c);
      if (node_root[gid]){
        out[(size_t)b*HH + j] = h;
        out[(size_t)BB*HH + (size_t)b*HH + j] = c;
      }
    }
    if (lvl < nlev){
      ph++;
      flagbar(flags, ph, ldsok);
    }
  }
}

// ---------------------------------------------------------------------------
extern "C" void kernel_launch(void* const* d_in, const int* in_sizes, int n_in,
                              void* d_out, int out_size, void* d_ws, size_t ws_size,
                              hipStream_t stream){
  const float* se  = (const float*)d_in[0];
  const float* gu  = (const float*)d_in[1];
  const float* Wih = (const float*)d_in[2];
  const float* Whh = (const float*)d_in[3];
  const float* bih = (const float*)d_in[4];
  const float* bhh = (const float*)d_in[5];
  const float* R1  = (const float*)d_in[6];
  const float* R2  = (const float*)d_in[7];
  const float* Wc  = (const float*)d_in[8];
  const float* bc  = (const float*)d_in[9];
  const int*   len = (const int*)d_in[10];
  float* out = (float*)d_out;                 // [2,16,1024] fp32

  float* ws = (float*)d_ws;
  size_t off = 0;
  float* R1t   = ws + off; off += (size_t)HH*RANKH;
  float* Gx    = ws + off; off += (size_t)BB*LL*NG4;     // [m][t][4096]
  float* Gxt   = ws + off; off += (size_t)BB*LL*NG4;     // [t][4096][m]
  float* hs    = ws + off; off += (size_t)BB*LL*HH;
  float* cs    = ws + off; off += (size_t)BB*LL*HH;
  float* nodeC = ws + off; off += (size_t)TOTN*HH;
  float* gates = ws + off; off += (size_t)MAXNPL*NG6;
  unsigned short* Wc_bf    = (unsigned short*)(ws + off); off += (size_t)NG6*K3H/2;
  unsigned short* hs_bf    = (unsigned short*)(ws + off); off += (size_t)BB*LL*HH/2;
  unsigned short* nodeH_bf = (unsigned short*)(ws + off); off += (size_t)TOTN*HH/2 + 512;
  unsigned short* zrow     = (unsigned short*)(ws + off); off += 512;  // 1024 zero bf16
  float* score = ws + off; off += 1024;
  float* snoi  = ws + off; off += 1024;
  unsigned* flags = (unsigned*)(ws + off); off += 512;   // byte flags: scan @0, tree @ +1024B
  int* ib = (int*)(ws + off);
  int* node_l    = ib; ib += 768;
  int* node_r    = ib; ib += 768;
  int* node_x    = ib; ib += 768;
  int* node_lvl  = ib; ib += 768;
  int* node_b    = ib; ib += 768;
  int* node_root = ib; ib += 768;
  int* level_count = ib; ib += 64;
  int* level_off   = ib; ib += 64;
  int* order       = ib; ib += 768;

  // 0. zero flag arrays + dummy zero row (ws poisoned every launch)
  k_init<<<1, 256, 0, stream>>>(flags, zrow);
  // 1. R1 transpose + Wc bf16 conversion
  k_transpose<<<dim3(32, 4), dim3(32, 8), 0, stream>>>(R1, R1t, RANKH, HH);
  k_cvt_bf16<<<(NG6*K3H)/1024, 256, 0, stream>>>(Wc, Wc_bf, NG6*K3H);
  // 2. input-side gate GEMM (+ both biases), then transpose for the scan
  k_gemm_gx<<<dim3(12, 64), 256, 0, stream>>>(se, Wih, bih, bhh, Gx, BB*LL, NG4, HH);
  k_gx_t<<<dim3(48, 16), 256, 0, stream>>>(Gx, Gxt);
  // 3. persistent recurrent LSTM scan (48 steps, byte-flag barriers)
  k_lstm_scan<<<256, 256, 0, stream>>>(Whh, Gxt, hs, cs, hs_bf,
                                       (unsigned char*)flags);
  // 4. per-position scores + gumbel noise (fp32)
  k_score<<<BB*LL, 128, 0, stream>>>(R1t, R2, hs, gu, score, snoi);
  // 5. tree structure
  k_build<<<1, 64, 0, stream>>>(score, snoi, len, node_l, node_r, node_x,
                                node_lvl, node_b, node_root,
                                level_count, level_off, order);
  // 6. persistent level-by-level nary composition (LDS-resident Wc)
  k_tree<<<256, 256, 0, stream>>>(Wc_bf, hs_bf, nodeH_bf, zrow, bc, cs, nodeC,
                                  node_l, node_r, node_x, node_b, node_root,
                                  level_count, level_off, order,
                                  gates, out, (unsigned char*)(flags + 256));
}

// Round 4
// 1056.424 us; speedup vs baseline: 1.9612x; 1.3676x over previous
//
#include <hip/hip_runtime.h>
#include <math.h>

#define BB 16
#define LL 48
#define HH 1024
#define NG4 4096      // 4*H
#define NG6 6144      // 6*H
#define K3H 3072      // 3*H
#define RANKH 128
#define MAXN 47       // max nodes per batch (len-1 <= 47)
#define TOTN (BB*MAXN)
#define MAXLVL 48
#define MAXNPL 384    // max nodes in one level

#define FSTRIDE 32    // dwords between block flags (128B line spacing)

typedef __attribute__((ext_vector_type(8))) short bf16x8;
typedef __attribute__((ext_vector_type(4))) float f32x4;

__device__ __forceinline__ float sigf(float x){ return 1.f/(1.f + expf(-x)); }

__device__ __forceinline__ unsigned short f2bf(float f){
  union { float f; unsigned u; } v; v.f = f;
  unsigned r = v.u + 0x7fff + ((v.u >> 16) & 1);
  return (unsigned short)(r >> 16);
}

// ---- LLC-coherent ops (device coherence point; bypass L1/L2, no allocate) ----
__device__ __forceinline__ void st_llc(float* p, float v){
  __hip_atomic_store(p, v, __ATOMIC_RELAXED, __HIP_MEMORY_SCOPE_AGENT);
}
__device__ __forceinline__ float ld_llc(const float* p){
  return __hip_atomic_load(p, __ATOMIC_RELAXED, __HIP_MEMORY_SCOPE_AGENT);
}
__device__ __forceinline__ void st_llc_u16(unsigned short* p, unsigned v){
  asm volatile("global_store_short %0, %1, off sc0 sc1" :: "v"(p), "v"(v) : "memory");
}
__device__ __forceinline__ void st_llc_u32(unsigned* p, unsigned v){
  asm volatile("global_store_dword %0, %1, off sc0 sc1" :: "v"(p), "v"(v) : "memory");
}
__device__ __forceinline__ void wait_vm0(){
  asm volatile("s_waitcnt vmcnt(0)" ::: "memory");
}

// Distributed-flag grid barrier: NO atomic RMW, NO writeback, NO invalidate.
// Each block owns a PRIVATE 128B line (flags[block*FSTRIDE]) so the 256
// arrival stores are full-dword writes to 256 distinct lines -> they land in
// parallel across LLC banks (no same-line partial-write serialization, which
// was the ~13us/step cost of the packed byte-flag variant: WRITE_SIZE 423MB
// of RMW merge-writebacks). Thread i polls flags[i*FSTRIDE]; 4-wave __all +
// LDS reduce. Data crossing the barrier must use LLC ops (st_llc*) or be
// first-read-after-write. flags MUST be zeroed every launch.
__device__ __forceinline__ void flagbar(unsigned* flags, unsigned p, int* ldsok){
  wait_vm0();
  __syncthreads();
  int tid = threadIdx.x;
  if (tid == 0)
    st_llc_u32(&flags[blockIdx.x*FSTRIDE], p);
  for (;;){
    unsigned v;
    asm volatile("global_load_dword %0, %1, off sc0 sc1"
                 : "=v"(v) : "v"(&flags[tid*FSTRIDE]));
    wait_vm0();
    int all64 = __all((int)(v >= p));
    if ((tid & 63) == 0) ldsok[tid >> 6] = all64;
    __syncthreads();
    if (ldsok[0] & ldsok[1] & ldsok[2] & ldsok[3]) break;
    __builtin_amdgcn_s_sleep(1);
    __syncthreads();
  }
}

// ---------------------------------------------------------------------------
// Zero flag arrays (scan: dwords [0..8191], tree: [8192..16383]) + zero row.
__global__ __launch_bounds__(256) void k_init(unsigned* flags, unsigned short* zrow){
  int tid = threadIdx.x;
  for (int i = tid; i < 16384; i += 256) flags[i] = 0u;
  for (int i = tid; i < 1024; i += 256) zrow[i] = 0;
}

// ---------------------------------------------------------------------------
// fp32 -> bf16 (RNE), vectorized. n multiple of 1024.
__global__ __launch_bounds__(256) void k_cvt_bf16(const float* __restrict__ in,
    unsigned short* __restrict__ out, int n){
  int i = (blockIdx.x*256 + threadIdx.x)*4;
  if (i >= n) return;
  float4 v = *(const float4*)(in + i);
  ushort4 o;
  o.x = f2bf(v.x); o.y = f2bf(v.y); o.z = f2bf(v.z); o.w = f2bf(v.w);
  *(ushort4*)(out + i) = o;
}

// ---------------------------------------------------------------------------
// Generic 32x32 LDS-tiled transpose: out[C][R] = in[R][C]^T  (R1 only)
__global__ __launch_bounds__(256) void k_transpose(const float* __restrict__ in,
                                                   float* __restrict__ out, int R, int C){
  __shared__ float t[32][33];
  int bx = blockIdx.x*32, by = blockIdx.y*32;
  int x = threadIdx.x, y = threadIdx.y;   // block (32,8)
  #pragma unroll
  for (int i = 0; i < 32; i += 8){
    int r = by + y + i, c = bx + x;
    if (r < R && c < C) t[y+i][x] = in[(size_t)r*C + c];
  }
  __syncthreads();
  #pragma unroll
  for (int i = 0; i < 32; i += 8){
    int r = bx + y + i, c = by + x;       // out dims [C][R]
    if (r < C && c < R) out[(size_t)r*R + c] = t[x][y+i];
  }
}

// ---------------------------------------------------------------------------
// Gx[m][n] = sum_k se[m][k]*Wih[n][k] + bih[n] + bhh[n]   (fp32 — decision path)
__global__ __launch_bounds__(256) void k_gemm_gx(const float* __restrict__ A,
    const float* __restrict__ Bw, const float* __restrict__ bih,
    const float* __restrict__ bhh, float* __restrict__ Cout, int M, int N, int K){
  __shared__ float as[16][68];
  __shared__ float bs[16][68];
  int m0 = blockIdx.x*64, n0 = blockIdx.y*64;
  int tid = threadIdx.x;
  int mt = tid & 15, nt = tid >> 4;
  float acc[4][4] = {};
  for (int k0 = 0; k0 < K; k0 += 16){
    #pragma unroll
    for (int it = 0; it < 4; ++it){
      int idx = it*256 + tid;
      int kk = idx & 15, mm = idx >> 4;
      as[kk][mm] = A[(size_t)(m0+mm)*K + k0 + kk];
      bs[kk][mm] = Bw[(size_t)(n0+mm)*K + k0 + kk];
    }
    __syncthreads();
    #pragma unroll
    for (int kk = 0; kk < 16; ++kk){
      float a4[4], b4[4];
      #pragma unroll
      for (int i = 0; i < 4; ++i) a4[i] = as[kk][mt*4+i];
      #pragma unroll
      for (int i = 0; i < 4; ++i) b4[i] = bs[kk][nt*4+i];
      #pragma unroll
      for (int i = 0; i < 4; ++i)
        #pragma unroll
        for (int j2 = 0; j2 < 4; ++j2) acc[i][j2] += a4[i]*b4[j2];
    }
    __syncthreads();
  }
  #pragma unroll
  for (int i = 0; i < 4; ++i){
    int m = m0 + mt*4 + i;
    #pragma unroll
    for (int j2 = 0; j2 < 4; ++j2){
      int n = n0 + nt*4 + j2;
      Cout[(size_t)m*N + n] = acc[i][j2] + bih[n] + bhh[n];
    }
  }
}

// ---------------------------------------------------------------------------
// Gx [m][t][4096] -> Gxt [t][4096][m]  (for coalesced per-step gate reads)
__global__ __launch_bounds__(256) void k_gx_t(const float* __restrict__ Gx,
                                              float* __restrict__ Gxt){
  __shared__ float t2[16][257];
  int t = blockIdx.x;       // 48
  int rc = blockIdx.y;      // 16 chunks of 256 rows
  int tid = threadIdx.x;
  #pragma unroll
  for (int m = 0; m < 16; ++m)
    t2[m][tid] = Gx[((size_t)(m*48 + t))*4096 + rc*256 + tid];
  __syncthreads();
  int rl = tid >> 4, m = tid & 15;
  #pragma unroll
  for (int i = 0; i < 16; ++i){
    int r = rc*256 + i*16 + rl;
    Gxt[((size_t)t*4096 + r)*16 + m] = t2[m][i*16 + rl];
  }
}

// ---------------------------------------------------------------------------
// Persistent LSTM scan: 256 blocks x 256 threads, 1 block/CU.
// h writes go through LLC (st_llc); h READS are plain cached loads
// (first-read-after-write: slice written once bypassing L2s, read once at
// lines the consumer L2 never held -> miss fetches fresh LLC data; the 32
// blocks of an XCD then share the line in L2).
// Whh held in registers, PERMUTED to match the linear LDS h layout:
//   lane kc owns k-indices {r*256 + 4*kc + j : r=0..3, j=0..3}
//   w[jj][r*4+j] = Whh[row][r*256 + 4*kc + j]
// so every LDS op is the canonical lanes-contiguous b128 pattern.
__global__ __launch_bounds__(256, 1) void k_lstm_scan(
    const float* __restrict__ Whh, const float* __restrict__ Gxt,
    float* __restrict__ hs, float* __restrict__ cs,
    unsigned short* __restrict__ hs_bf, unsigned* __restrict__ flags){
  __shared__ float smem[17408];   // 68KB: h-stage [16][1024] fp32; overlaid by reduce partials
  __shared__ float gbuf[4*64];
  __shared__ float cbuf[64];
  __shared__ int ldsok[4];
  int tid = threadIdx.x;
  int g = tid >> 6, kc = tid & 63;
  int j0 = blockIdx.x * 4;
  float w[4][16];
  #pragma unroll
  for (int jj = 0; jj < 4; ++jj){
    const float* src = Whh + (size_t)(g*1024 + j0 + jj)*1024 + kc*4;
    #pragma unroll
    for (int r = 0; r < 4; ++r){
      float4 v = *(const float4*)(src + r*256);
      w[jj][r*4+0]=v.x; w[jj][r*4+1]=v.y; w[jj][r*4+2]=v.z; w[jj][r*4+3]=v.w;
    }
  }
  if (tid < 64) cbuf[tid] = 0.f;
  for (int t = 0; t < LL; ++t){
    // prefetch this step's x-gate contribution for gate group g (read-only
    // data written before launch -> plain cached load, issued before h work)
    float gx = Gxt[((size_t)t*NG4 + g*1024 + j0 + (kc & 3))*16 + (kc >> 2)];
    float G = 0.f;
    if (t > 0){
      // h_{t-1}: plain cached dwordx4 loads (first-read-after-write, L2-shared)
      f32x4 hv[16];
      #pragma unroll
      for (int m = 0; m < 16; ++m)
        hv[m] = *(const f32x4*)(hs + ((size_t)(m*LL + t-1))*HH + (tid<<2));
      #pragma unroll
      for (int m = 0; m < 16; ++m)
        *(f32x4*)&smem[m*1024 + (tid<<2)] = hv[m];   // lanes contiguous: conflict-free
      __syncthreads();
      float acc[4][16];
      #pragma unroll 4
      for (int m = 0; m < 16; ++m){
        const float* hb = &smem[m*1024 + (kc<<2)];
        float4 h0 = *(const float4*)(hb);        // canonical b128: lanes at 16B stride
        float4 h1 = *(const float4*)(hb+256);
        float4 h2 = *(const float4*)(hb+512);
        float4 h3 = *(const float4*)(hb+768);
        #pragma unroll
        for (int jj = 0; jj < 4; ++jj){
          float s = w[jj][0]*h0.x + w[jj][1]*h0.y + w[jj][2]*h0.z + w[jj][3]*h0.w
                  + w[jj][4]*h1.x + w[jj][5]*h1.y + w[jj][6]*h1.z + w[jj][7]*h1.w
                  + w[jj][8]*h2.x + w[jj][9]*h2.y + w[jj][10]*h2.z + w[jj][11]*h2.w
                  + w[jj][12]*h3.x + w[jj][13]*h3.y + w[jj][14]*h3.z + w[jj][15]*h3.w;
          acc[jj][m] = s;
        }
      }
      __syncthreads();   // h reads done; smem reused as reduce partials
      #pragma unroll
      for (int m = 0; m < 16; ++m){
        float4 v;
        v.x = acc[0][m]; v.y = acc[1][m]; v.z = acc[2][m]; v.w = acc[3][m];
        *(float4*)&smem[(size_t)(g*64 + kc)*68 + m*4] = v;
      }
      __syncthreads();
      {
        float s0=0.f,s1=0.f,s2=0.f,s3=0.f;
        #pragma unroll 4
        for (int l = 0; l < 64; l += 4){
          s0 += smem[(size_t)(g*64 + l  )*68 + kc];
          s1 += smem[(size_t)(g*64 + l+1)*68 + kc];
          s2 += smem[(size_t)(g*64 + l+2)*68 + kc];
          s3 += smem[(size_t)(g*64 + l+3)*68 + kc];
        }
        G = (s0+s1)+(s2+s3);
      }
    }
    gbuf[g*64 + kc] = G + gx;   // recurrent + input parts combined
    __syncthreads();
    if (g == 0){
      int o = kc;               // o = m*4 + jj
      int jj = o & 3, m = o >> 2;
      float gi = gbuf[0*64 + o];
      float gf = gbuf[1*64 + o];
      float gu = gbuf[2*64 + o];
      float go = gbuf[3*64 + o];
      float cp = cbuf[o];
      float c = sigf(gf)*cp + sigf(gi)*tanhf(gu);
      float h = sigf(go)*tanhf(c);
      cbuf[o] = c;
      size_t oidx = ((size_t)(m*LL + t))*HH + j0 + jj;
      st_llc(&hs[oidx], h);     // LLC write-through: visible without fences
      cs[oidx] = c;             // consumed after kernel boundary only
      hs_bf[oidx] = f2bf(h);    // consumed after kernel boundary only
    }
    if (t < LL-1)
      flagbar(flags, (unsigned)(t+1), ldsok);
  }
}

// ---------------------------------------------------------------------------
// Per-position rank-MLP score + gumbel noise (fp32 — decision path).
__global__ __launch_bounds__(128) void k_score(const float* __restrict__ R1t,
    const float* __restrict__ R2, const float* __restrict__ hs,
    const float* __restrict__ gumbel_u, float* __restrict__ score,
    float* __restrict__ snoisy){
  __shared__ float hsm[HH];
  __shared__ float red[128];
  int bt = blockIdx.x;
  int tid = threadIdx.x;
  for (int i = tid; i < HH; i += 128) hsm[i] = hs[(size_t)bt*HH + i];
  __syncthreads();
  float acc = 0.f;
  for (int k = 0; k < HH; ++k) acc += R1t[(size_t)k*RANKH + tid] * hsm[k];
  red[tid] = fmaxf(acc, 0.f) * R2[tid];
  __syncthreads();
  for (int s = 64; s > 0; s >>= 1){
    if (tid < s) red[tid] += red[tid+s];
    __syncthreads();
  }
  if (tid == 0){
    float s = red[0];
    float u = gumbel_u[bt];
    float noise = -logf(-logf(u));
    score[bt]  = s;
    snoisy[bt] = s + noise;
  }
}

// ---------------------------------------------------------------------------
// Build the tree structure for all batches. 1 block, 64 threads.
// level_count[0] <- number of levels (max height).
__global__ __launch_bounds__(64) void k_build(const float* __restrict__ score,
    const float* __restrict__ snoisy, const int* __restrict__ length,
    int* __restrict__ node_l, int* __restrict__ node_r, int* __restrict__ node_x,
    int* __restrict__ node_lvl, int* __restrict__ node_b, int* __restrict__ node_root,
    int* __restrict__ level_count, int* __restrict__ level_off, int* __restrict__ order){
  __shared__ float sc[BB*LL], sn[BB*LL];
  __shared__ int lcount[MAXLVL+1], lcur[MAXLVL+1], loff[MAXLVL+1];
  __shared__ int percnt[BB];
  int tid = threadIdx.x;
  for (int i = tid; i < BB*LL; i += 64){ sc[i] = score[i]; sn[i] = snoisy[i]; }
  for (int i = tid; i <= MAXLVL; i += 64){ lcount[i] = 0; lcur[i] = 0; }
  __syncthreads();
  if (tid < BB){
    int b = tid;
    int len = length[b];
    if (len > LL) len = LL;
    int qs[MAXN], qe[MAXN], qn[MAXN];
    int qh = 0, qt = 0, cnt = 0;
    int rootn = cnt++;
    qs[qt] = 0; qe[qt] = len; qn[qt] = rootn; qt++;
    while (qh < qt){
      int s0 = qs[qh], e0 = qe[qh], nid = qn[qh]; qh++;
      float best = sc[b*LL + s0]; int pos = s0;
      for (int t2 = s0+1; t2 < e0; ++t2){
        float v = sc[b*LL + t2];
        if (v > best){ best = v; pos = t2; }
      }
      float bestn = sn[b*LL + s0]; int js = s0;
      for (int t2 = s0+1; t2 < e0; ++t2){
        float v = sn[b*LL + t2];
        if (v > bestn){ bestn = v; js = t2; }
      }
      int gid = b*MAXN + nid;
      node_x[gid] = js;
      node_b[gid] = b;
      node_root[gid] = (nid == 0) ? 1 : 0;
      int ln = pos - s0, enc_l, enc_r;
      if (ln <= 0) enc_l = -1;
      else if (ln == 1) enc_l = 10000 + s0;
      else { int c2 = cnt++; enc_l = b*MAXN + c2; qs[qt]=s0; qe[qt]=pos; qn[qt]=c2; qt++; }
      int rn = e0 - (pos+1);
      if (rn <= 0) enc_r = -1;
      else if (rn == 1) enc_r = 10000 + (pos+1);
      else { int c2 = cnt++; enc_r = b*MAXN + c2; qs[qt]=pos+1; qe[qt]=e0; qn[qt]=c2; qt++; }
      node_l[gid] = enc_l; node_r[gid] = enc_r;
    }
    for (int i = cnt-1; i >= 0; --i){
      int gid = b*MAXN + i;
      int el = node_l[gid], er = node_r[gid];
      int llv = (el >= 0 && el < 10000) ? node_lvl[el] : 0;
      int rlv = (er >= 0 && er < 10000) ? node_lvl[er] : 0;
      node_lvl[gid] = 1 + (llv > rlv ? llv : rlv);
    }
    for (int i = 0; i < cnt; ++i) atomicAdd(&lcount[node_lvl[b*MAXN + i]], 1);
    percnt[b] = cnt;
  }
  __syncthreads();
  if (tid == 0){
    int off = 0, nlev = 0;
    for (int lv = 1; lv <= MAXLVL; ++lv){
      loff[lv] = off;
      level_off[lv] = off;
      level_count[lv] = lcount[lv];
      if (lcount[lv] > 0) nlev = lv;
      off += lcount[lv];
    }
    level_count[0] = nlev;
  }
  __syncthreads();
  if (tid < BB){
    int b = tid;
    int cnt = percnt[b];
    for (int i = 0; i < cnt; ++i){
      int gid = b*MAXN + i;
      int lv = node_lvl[gid];
      int p = atomicAdd(&lcur[lv], 1);
      order[loff[lv] + p] = gid;
    }
  }
}

// ---------------------------------------------------------------------------
// Persistent tree composition, spread-flag barriers, NO wb/inv.
// Wc is LDS-RESIDENT: each of the 256 blocks owns 24 Wc rows (144KB, loaded
// once, XOR-swizzled). Per level every block computes its 24 gate columns for
// ALL nodes of the level; A-frags are L2-broadcast reads, B from LDS.
// Coherence protocol:
//  - gates: LLC stores (A) -> LLC loads (B)
//  - nodeH_bf / nodeC: LLC stores (B) -> normal cached first-reads later
//  - Wc_bf / hs_bf / order / node_*: read-only, cached.
__global__ __launch_bounds__(256, 1) void k_tree(
    const unsigned short* __restrict__ Wc_bf,
    const unsigned short* __restrict__ hs_bf,
    unsigned short* __restrict__ nodeH_bf,
    const unsigned short* __restrict__ zrow,
    const float* __restrict__ bc, const float* __restrict__ cs,
    float* __restrict__ nodeC,
    const int* __restrict__ node_l, const int* __restrict__ node_r,
    const int* __restrict__ node_x, const int* __restrict__ node_b,
    const int* __restrict__ node_root, const int* __restrict__ level_count,
    const int* __restrict__ level_off, const int* __restrict__ order,
    float* __restrict__ gates, float* __restrict__ out,
    unsigned* __restrict__ flags){
  __shared__ __align__(16) unsigned char wlds[24*6144];   // 144KB Wc slice
  __shared__ int ldsok[4];
  int tid = threadIdx.x;
  int lane = tid & 63;
  int wave = tid >> 6;
  int fr = lane & 15;          // fragment row (A: node slot, B: Wc row)
  int fkq = lane >> 4;         // k-quarter 0..3
  int fk  = fkq * 8;           // element offset within 32-elem k-chunk
  int fkb = fkq * 16;          // byte offset
  int swz = (fr & 7) << 4;     // XOR swizzle (G4: row-major stride-6144B tile)
  int base0 = fr * 6144;               // n-tile 0: rows 0..15
  int base1 = (16 + (fr & 7)) * 6144;  // n-tile 1: rows 16..23 (dup for fr>=8)
  int rg24 = blockIdx.x * 24;  // this block's 24 Wc rows / gate columns

  // ---- one-time: stage 24 Wc rows into LDS, swizzled ----
  for (int i = tid; i < 24*384; i += 256){
    int row = i / 384;
    int ch  = i - row*384;     // 16B chunk within row
    uint4 v = *(const uint4*)(Wc_bf + (size_t)(rg24 + row)*K3H + ch*8);
    *(uint4*)(wlds + row*6144 + ((ch*16) ^ ((row & 7) << 4))) = v;
  }
  __syncthreads();

  int nlev = level_count[0];
  unsigned ph = 0;
  for (int lvl = 1; lvl <= nlev; ++lvl){
    int n = level_count[lvl];
    int loffv = level_off[lvl];
    // ---- Phase A: all nodes x this block's 24 Wc rows, B from LDS ----
    int mtiles = (n + 15) >> 4;
    for (int mt = wave; mt < mtiles; mt += 4){
      int slot = mt*16 + fr;
      const unsigned short *pa0, *pa1, *pa2;
      if (slot < n){
        int gid = order[loffv + slot];
        int b = node_b[gid];
        int el = node_l[gid], er = node_r[gid], xt = node_x[gid];
        pa0 = (el < 0) ? zrow : (el >= 10000 ? hs_bf + (size_t)(b*LL + (el-10000))*HH
                                             : nodeH_bf + (size_t)el*HH);
        pa1 = (er < 0) ? zrow : (er >= 10000 ? hs_bf + (size_t)(b*LL + (er-10000))*HH
                                             : nodeH_bf + (size_t)er*HH);
        pa2 = hs_bf + (size_t)(b*LL + xt)*HH;
      } else { pa0 = zrow; pa1 = zrow; pa2 = zrow; }
      const unsigned short* pa[3] = {pa0, pa1, pa2};
      f32x4 acc0 = {0.f,0.f,0.f,0.f};
      f32x4 acc1 = {0.f,0.f,0.f,0.f};
      #pragma unroll
      for (int part = 0; part < 3; ++part){
        const unsigned short* ap = pa[part] + fk;
        #pragma unroll 8
        for (int kcc = 0; kcc < 1024; kcc += 32){
          bf16x8 a = *(const bf16x8*)(ap + kcc);
          int xb = part*2048 + kcc*2 + fkb;
          bf16x8 b0 = *(const bf16x8*)(wlds + base0 + (xb ^ swz));
          bf16x8 b1 = *(const bf16x8*)(wlds + base1 + (xb ^ swz));
          acc0 = __builtin_amdgcn_mfma_f32_16x16x32_bf16(a, b0, acc0, 0, 0, 0);
          acc1 = __builtin_amdgcn_mfma_f32_16x16x32_bf16(a, b1, acc1, 0, 0, 0);
        }
      }
      int m0 = mt*16 + fkq*4;
      #pragma unroll
      for (int r = 0; r < 4; ++r){
        int m = m0 + r;
        if (m < n){
          st_llc(&gates[(size_t)m*NG6 + rg24 + fr], acc0[r]);
          if (fr < 8)
            st_llc(&gates[(size_t)m*NG6 + rg24 + 16 + fr], acc1[r]);
        }
      }
    }
    ph++;
    flagbar(flags, ph, ldsok);
    // ---- Phase B: epilogue ----
    int items = n * 4;
    for (int it = blockIdx.x; it < items; it += 256){
      int ns = it >> 2;
      int j = (it & 3)*256 + tid;
      int gid = order[loffv + ns];
      int b = node_b[gid];
      int el = node_l[gid], er = node_r[gid], xt = node_x[gid];
      float gg[6];
      #pragma unroll
      for (int q = 0; q < 6; ++q)
        gg[q] = bc[q*HH + j] + ld_llc(&gates[(size_t)ns*NG6 + q*HH + j]);
      float lc = (el < 0) ? 0.f : (el >= 10000 ? cs[(size_t)(b*LL + (el-10000))*HH + j]
                                               : nodeC[(size_t)el*HH + j]);
      float rc = (er < 0) ? 0.f : (er >= 10000 ? cs[(size_t)(b*LL + (er-10000))*HH + j]
                                               : nodeC[(size_t)er*HH + j]);
      float xc = cs[(size_t)(b*LL + xt)*HH + j];
      float c = sigf(gg[0])*tanhf(gg[4]) + sigf(gg[1])*lc + sigf(gg[2])*rc + sigf(gg[3])*xc;
      float h = sigf(gg[5])*tanhf(c);
      st_llc_u16(&nodeH_bf[(size_t)gid*HH + j], (unsigned)f2bf(h));
      st_llc(&nodeC[(size_t)gid*HH + j], c);
      if (node_root[gid]){
        out[(size_t)b*HH + j] = h;
        out[(size_t)BB*HH + (size_t)b*HH + j] = c;
      }
    }
    if (lvl < nlev){
      ph++;
      flagbar(flags, ph, ldsok);
    }
  }
}

// ---------------------------------------------------------------------------
extern "C" void kernel_launch(void* const* d_in, const int* in_sizes, int n_in,
                              void* d_out, int out_size, void* d_ws, size_t ws_size,
                              hipStream_t stream){
  const float* se  = (const float*)d_in[0];
  const float* gu  = (const float*)d_in[1];
  const float* Wih = (const float*)d_in[2];
  const float* Whh = (const float*)d_in[3];
  const float* bih = (const float*)d_in[4];
  const float* bhh = (const float*)d_in[5];
  const float* R1  = (const float*)d_in[6];
  const float* R2  = (const float*)d_in[7];
  const float* Wc  = (const float*)d_in[8];
  const float* bc  = (const float*)d_in[9];
  const int*   len = (const int*)d_in[10];
  float* out = (float*)d_out;                 // [2,16,1024] fp32

  float* ws = (float*)d_ws;
  size_t off = 0;
  float* R1t   = ws + off; off += (size_t)HH*RANKH;
  float* Gx    = ws + off; off += (size_t)BB*LL*NG4;     // [m][t][4096]
  float* Gxt   = ws + off; off += (size_t)BB*LL*NG4;     // [t][4096][m]
  float* hs    = ws + off; off += (size_t)BB*LL*HH;
  float* cs    = ws + off; off += (size_t)BB*LL*HH;
  float* nodeC = ws + off; off += (size_t)TOTN*HH;
  float* gates = ws + off; off += (size_t)MAXNPL*NG6;
  unsigned short* Wc_bf    = (unsigned short*)(ws + off); off += (size_t)NG6*K3H/2;
  unsigned short* hs_bf    = (unsigned short*)(ws + off); off += (size_t)BB*LL*HH/2;
  unsigned short* nodeH_bf = (unsigned short*)(ws + off); off += (size_t)TOTN*HH/2 + 512;
  unsigned short* zrow     = (unsigned short*)(ws + off); off += 512;  // 1024 zero bf16
  float* score = ws + off; off += 1024;
  float* snoi  = ws + off; off += 1024;
  unsigned* flags = (unsigned*)(ws + off); off += 16384; // spread flags: scan @0, tree @ +8192 dwords (64KB total)
  int* ib = (int*)(ws + off);
  int* node_l    = ib; ib += 768;
  int* node_r    = ib; ib += 768;
  int* node_x    = ib; ib += 768;
  int* node_lvl  = ib; ib += 768;
  int* node_b    = ib; ib += 768;
  int* node_root = ib; ib += 768;
  int* level_count = ib; ib += 64;
  int* level_off   = ib; ib += 64;
  int* order       = ib; ib += 768;

  // 0. zero flag arrays + dummy zero row (ws poisoned every launch)
  k_init<<<1, 256, 0, stream>>>(flags, zrow);
  // 1. R1 transpose + Wc bf16 conversion
  k_transpose<<<dim3(32, 4), dim3(32, 8), 0, stream>>>(R1, R1t, RANKH, HH);
  k_cvt_bf16<<<(NG6*K3H)/1024, 256, 0, stream>>>(Wc, Wc_bf, NG6*K3H);
  // 2. input-side gate GEMM (+ both biases), then transpose for the scan
  k_gemm_gx<<<dim3(12, 64), 256, 0, stream>>>(se, Wih, bih, bhh, Gx, BB*LL, NG4, HH);
  k_gx_t<<<dim3(48, 16), 256, 0, stream>>>(Gx, Gxt);
  // 3. persistent recurrent LSTM scan (48 steps, spread-flag barriers)
  k_lstm_scan<<<256, 256, 0, stream>>>(Whh, Gxt, hs, cs, hs_bf, flags);
  // 4. per-position scores + gumbel noise (fp32)
  k_score<<<BB*LL, 128, 0, stream>>>(R1t, R2, hs, gu, score, snoi);
  // 5. tree structure
  k_build<<<1, 64, 0, stream>>>(score, snoi, len, node_l, node_r, node_x,
                                node_lvl, node_b, node_root,
                                level_count, level_off, order);
  // 6. persistent level-by-level nary composition (LDS-resident Wc)
  k_tree<<<256, 256, 0, stream>>>(Wc_bf, hs_bf, nodeH_bf, zrow, bc, cs, nodeC,
                                  node_l, node_r, node_x, node_b, node_root,
                                  level_count, level_off, order,
                                  gates, out, flags + 8192);
}

// Round 5
// 1052.463 us; speedup vs baseline: 1.9685x; 1.0038x over previous
//
#include <hip/hip_runtime.h>
#include <math.h>

#define BB 16
#define LL 48
#define HH 1024
#define NG4 4096      // 4*H
#define NG6 6144      // 6*H
#define K3H 3072      // 3*H
#define RANKH 128
#define MAXN 47       // max nodes per batch (len-1 <= 47)
#define TOTN (BB*MAXN)
#define MAXLVL 48
#define MAXNPL 384    // max nodes in one level

#define FSTRIDE 32    // dwords between flag lines (128B line spacing)
#define NRELEASE 16   // release-flag replicas (lines 256..271)
#define FDOM 16384    // dwords per barrier domain (scan @0, tree @FDOM)

typedef __attribute__((ext_vector_type(8))) short bf16x8;
typedef __attribute__((ext_vector_type(4))) float f32x4;

__device__ __forceinline__ float sigf(float x){ return 1.f/(1.f + expf(-x)); }

__device__ __forceinline__ unsigned short f2bf(float f){
  union { float f; unsigned u; } v; v.f = f;
  unsigned r = v.u + 0x7fff + ((v.u >> 16) & 1);
  return (unsigned short)(r >> 16);
}

// ---- LLC-coherent ops (device coherence point; bypass L1/L2, no allocate) ----
__device__ __forceinline__ void st_llc(float* p, float v){
  __hip_atomic_store(p, v, __ATOMIC_RELAXED, __HIP_MEMORY_SCOPE_AGENT);
}
__device__ __forceinline__ float ld_llc(const float* p){
  return __hip_atomic_load(p, __ATOMIC_RELAXED, __HIP_MEMORY_SCOPE_AGENT);
}
__device__ __forceinline__ void st_llc_u16(unsigned short* p, unsigned v){
  asm volatile("global_store_short %0, %1, off sc0 sc1" :: "v"(p), "v"(v) : "memory");
}
__device__ __forceinline__ void st_llc_u32(unsigned* p, unsigned v){
  asm volatile("global_store_dword %0, %1, off sc0 sc1" :: "v"(p), "v"(v) : "memory");
}
__device__ __forceinline__ unsigned ld_llc_u32(const unsigned* p){
  unsigned v;
  asm volatile("global_load_dword %0, %1, off sc0 sc1" : "=v"(v) : "v"(p));
  return v;
}
__device__ __forceinline__ void wait_vm0(){
  asm volatile("s_waitcnt vmcnt(0)" ::: "memory");
}

// Centralized two-phase grid barrier: NO atomic RMW, NO writeback, NO invalidate.
// Arrival: each block stores phase p to its PRIVATE 128B line (parallel across
// LLC banks). Aggregation: ONLY block 0 polls the 256 arrival lines (one
// thread per line -> single reader per line, one LLC round trip), then stores
// p to NRELEASE replica lines. Release: every other block has ONE thread poll
// replica (blockIdx&15) -> 16 readers/line. This removes the O(256^2)
// uncached poll-request storm (65K reqs/iter on 256 banks) of the all-blocks-
// poll-all-lines variant. Data crossing the barrier must use LLC ops
// (st_llc*) or be first-read-after-write. flags MUST be zeroed every launch.
__device__ __forceinline__ void flagbar(unsigned* flags, unsigned p, int* ldsok){
  wait_vm0();
  __syncthreads();
  int tid = threadIdx.x;
  if (tid == 0)
    st_llc_u32(&flags[blockIdx.x*FSTRIDE], p);
  if (blockIdx.x == 0){
    for (;;){
      unsigned v = ld_llc_u32(&flags[tid*FSTRIDE]);
      wait_vm0();
      int all64 = __all((int)(v >= p));
      if ((tid & 63) == 0) ldsok[tid >> 6] = all64;
      __syncthreads();
      if (ldsok[0] & ldsok[1] & ldsok[2] & ldsok[3]) break;
      __builtin_amdgcn_s_sleep(1);
      __syncthreads();
    }
    if (tid < NRELEASE)
      st_llc_u32(&flags[(256 + tid)*FSTRIDE], p);
  } else {
    const unsigned* rl = &flags[(256 + (blockIdx.x & (NRELEASE-1)))*FSTRIDE];
    for (;;){
      if (tid == 0){
        unsigned v = ld_llc_u32(rl);
        wait_vm0();
        ldsok[0] = (int)(v >= p);
      }
      __syncthreads();
      if (ldsok[0]) break;
      __builtin_amdgcn_s_sleep(1);
      __syncthreads();
    }
  }
}

// ---------------------------------------------------------------------------
// Zero both flag domains + the zero dummy row.
__global__ __launch_bounds__(256) void k_init(unsigned* flags, unsigned short* zrow){
  int tid = threadIdx.x;
  for (int i = tid; i < 2*FDOM; i += 256) flags[i] = 0u;
  for (int i = tid; i < 1024; i += 256) zrow[i] = 0;
}

// ---------------------------------------------------------------------------
// fp32 -> bf16 (RNE), vectorized. n multiple of 1024.
__global__ __launch_bounds__(256) void k_cvt_bf16(const float* __restrict__ in,
    unsigned short* __restrict__ out, int n){
  int i = (blockIdx.x*256 + threadIdx.x)*4;
  if (i >= n) return;
  float4 v = *(const float4*)(in + i);
  ushort4 o;
  o.x = f2bf(v.x); o.y = f2bf(v.y); o.z = f2bf(v.z); o.w = f2bf(v.w);
  *(ushort4*)(out + i) = o;
}

// ---------------------------------------------------------------------------
// Generic 32x32 LDS-tiled transpose: out[C][R] = in[R][C]^T  (R1 only)
__global__ __launch_bounds__(256) void k_transpose(const float* __restrict__ in,
                                                   float* __restrict__ out, int R, int C){
  __shared__ float t[32][33];
  int bx = blockIdx.x*32, by = blockIdx.y*32;
  int x = threadIdx.x, y = threadIdx.y;   // block (32,8)
  #pragma unroll
  for (int i = 0; i < 32; i += 8){
    int r = by + y + i, c = bx + x;
    if (r < R && c < C) t[y+i][x] = in[(size_t)r*C + c];
  }
  __syncthreads();
  #pragma unroll
  for (int i = 0; i < 32; i += 8){
    int r = bx + y + i, c = by + x;       // out dims [C][R]
    if (r < C && c < R) out[(size_t)r*R + c] = t[x][y+i];
  }
}

// ---------------------------------------------------------------------------
// Gx[m][n] = sum_k se[m][k]*Wih[n][k] + bih[n] + bhh[n]   (fp32 — decision path)
__global__ __launch_bounds__(256) void k_gemm_gx(const float* __restrict__ A,
    const float* __restrict__ Bw, const float* __restrict__ bih,
    const float* __restrict__ bhh, float* __restrict__ Cout, int M, int N, int K){
  __shared__ float as[16][68];
  __shared__ float bs[16][68];
  int m0 = blockIdx.x*64, n0 = blockIdx.y*64;
  int tid = threadIdx.x;
  int mt = tid & 15, nt = tid >> 4;
  float acc[4][4] = {};
  for (int k0 = 0; k0 < K; k0 += 16){
    #pragma unroll
    for (int it = 0; it < 4; ++it){
      int idx = it*256 + tid;
      int kk = idx & 15, mm = idx >> 4;
      as[kk][mm] = A[(size_t)(m0+mm)*K + k0 + kk];
      bs[kk][mm] = Bw[(size_t)(n0+mm)*K + k0 + kk];
    }
    __syncthreads();
    #pragma unroll
    for (int kk = 0; kk < 16; ++kk){
      float a4[4], b4[4];
      #pragma unroll
      for (int i = 0; i < 4; ++i) a4[i] = as[kk][mt*4+i];
      #pragma unroll
      for (int i = 0; i < 4; ++i) b4[i] = bs[kk][nt*4+i];
      #pragma unroll
      for (int i = 0; i < 4; ++i)
        #pragma unroll
        for (int j2 = 0; j2 < 4; ++j2) acc[i][j2] += a4[i]*b4[j2];
    }
    __syncthreads();
  }
  #pragma unroll
  for (int i = 0; i < 4; ++i){
    int m = m0 + mt*4 + i;
    #pragma unroll
    for (int j2 = 0; j2 < 4; ++j2){
      int n = n0 + nt*4 + j2;
      Cout[(size_t)m*N + n] = acc[i][j2] + bih[n] + bhh[n];
    }
  }
}

// ---------------------------------------------------------------------------
// Gx [m][t][4096] -> Gxt [t][4096][m]  (for coalesced per-step gate reads)
__global__ __launch_bounds__(256) void k_gx_t(const float* __restrict__ Gx,
                                              float* __restrict__ Gxt){
  __shared__ float t2[16][257];
  int t = blockIdx.x;       // 48
  int rc = blockIdx.y;      // 16 chunks of 256 rows
  int tid = threadIdx.x;
  #pragma unroll
  for (int m = 0; m < 16; ++m)
    t2[m][tid] = Gx[((size_t)(m*48 + t))*4096 + rc*256 + tid];
  __syncthreads();
  int rl = tid >> 4, m = tid & 15;
  #pragma unroll
  for (int i = 0; i < 16; ++i){
    int r = rc*256 + i*16 + rl;
    Gxt[((size_t)t*4096 + r)*16 + m] = t2[m][i*16 + rl];
  }
}

// ---------------------------------------------------------------------------
// Persistent LSTM scan: 256 blocks x 256 threads, 1 block/CU.
// h writes go through LLC (st_llc); h READS are plain cached loads
// (first-read-after-write: slice written once bypassing L2s, read once at
// lines the consumer L2 never held -> miss fetches fresh LLC data; the 32
// blocks of an XCD then share the line in L2).
// Whh held in registers, PERMUTED to match the linear LDS h layout:
//   lane kc owns k-indices {r*256 + 4*kc + j : r=0..3, j=0..3}
//   w[jj][r*4+j] = Whh[row][r*256 + 4*kc + j]
// so every LDS op is the canonical lanes-contiguous b128 pattern.
__global__ __launch_bounds__(256, 1) void k_lstm_scan(
    const float* __restrict__ Whh, const float* __restrict__ Gxt,
    float* __restrict__ hs, float* __restrict__ cs,
    unsigned short* __restrict__ hs_bf, unsigned* __restrict__ flags){
  __shared__ float smem[17408];   // 68KB: h-stage [16][1024] fp32; overlaid by reduce partials
  __shared__ float gbuf[4*64];
  __shared__ float cbuf[64];
  __shared__ int ldsok[4];
  int tid = threadIdx.x;
  int g = tid >> 6, kc = tid & 63;
  int j0 = blockIdx.x * 4;
  float w[4][16];
  #pragma unroll
  for (int jj = 0; jj < 4; ++jj){
    const float* src = Whh + (size_t)(g*1024 + j0 + jj)*1024 + kc*4;
    #pragma unroll
    for (int r = 0; r < 4; ++r){
      float4 v = *(const float4*)(src + r*256);
      w[jj][r*4+0]=v.x; w[jj][r*4+1]=v.y; w[jj][r*4+2]=v.z; w[jj][r*4+3]=v.w;
    }
  }
  if (tid < 64) cbuf[tid] = 0.f;
  for (int t = 0; t < LL; ++t){
    // prefetch this step's x-gate contribution for gate group g (read-only
    // data written before launch -> plain cached load, issued before h work)
    float gx = Gxt[((size_t)t*NG4 + g*1024 + j0 + (kc & 3))*16 + (kc >> 2)];
    float G = 0.f;
    if (t > 0){
      // h_{t-1}: plain cached dwordx4 loads (first-read-after-write, L2-shared)
      f32x4 hv[16];
      #pragma unroll
      for (int m = 0; m < 16; ++m)
        hv[m] = *(const f32x4*)(hs + ((size_t)(m*LL + t-1))*HH + (tid<<2));
      #pragma unroll
      for (int m = 0; m < 16; ++m)
        *(f32x4*)&smem[m*1024 + (tid<<2)] = hv[m];   // lanes contiguous: conflict-free
      __syncthreads();
      float acc[4][16];
      #pragma unroll 4
      for (int m = 0; m < 16; ++m){
        const float* hb = &smem[m*1024 + (kc<<2)];
        float4 h0 = *(const float4*)(hb);        // canonical b128: lanes at 16B stride
        float4 h1 = *(const float4*)(hb+256);
        float4 h2 = *(const float4*)(hb+512);
        float4 h3 = *(const float4*)(hb+768);
        #pragma unroll
        for (int jj = 0; jj < 4; ++jj){
          float s = w[jj][0]*h0.x + w[jj][1]*h0.y + w[jj][2]*h0.z + w[jj][3]*h0.w
                  + w[jj][4]*h1.x + w[jj][5]*h1.y + w[jj][6]*h1.z + w[jj][7]*h1.w
                  + w[jj][8]*h2.x + w[jj][9]*h2.y + w[jj][10]*h2.z + w[jj][11]*h2.w
                  + w[jj][12]*h3.x + w[jj][13]*h3.y + w[jj][14]*h3.z + w[jj][15]*h3.w;
          acc[jj][m] = s;
        }
      }
      __syncthreads();   // h reads done; smem reused as reduce partials
      #pragma unroll
      for (int m = 0; m < 16; ++m){
        float4 v;
        v.x = acc[0][m]; v.y = acc[1][m]; v.z = acc[2][m]; v.w = acc[3][m];
        *(float4*)&smem[(size_t)(g*64 + kc)*68 + m*4] = v;
      }
      __syncthreads();
      {
        float s0=0.f,s1=0.f,s2=0.f,s3=0.f;
        #pragma unroll 4
        for (int l = 0; l < 64; l += 4){
          s0 += smem[(size_t)(g*64 + l  )*68 + kc];
          s1 += smem[(size_t)(g*64 + l+1)*68 + kc];
          s2 += smem[(size_t)(g*64 + l+2)*68 + kc];
          s3 += smem[(size_t)(g*64 + l+3)*68 + kc];
        }
        G = (s0+s1)+(s2+s3);
      }
    }
    gbuf[g*64 + kc] = G + gx;   // recurrent + input parts combined
    __syncthreads();
    if (g == 0){
      int o = kc;               // o = m*4 + jj
      int jj = o & 3, m = o >> 2;
      float gi = gbuf[0*64 + o];
      float gf = gbuf[1*64 + o];
      float gu = gbuf[2*64 + o];
      float go = gbuf[3*64 + o];
      float cp = cbuf[o];
      float c = sigf(gf)*cp + sigf(gi)*tanhf(gu);
      float h = sigf(go)*tanhf(c);
      cbuf[o] = c;
      size_t oidx = ((size_t)(m*LL + t))*HH + j0 + jj;
      st_llc(&hs[oidx], h);     // LLC write-through: visible without fences
      cs[oidx] = c;             // consumed after kernel boundary only
      hs_bf[oidx] = f2bf(h);    // consumed after kernel boundary only
    }
    if (t < LL-1)
      flagbar(flags, (unsigned)(t+1), ldsok);
  }
}

// ---------------------------------------------------------------------------
// Per-position rank-MLP score + gumbel noise (fp32 — decision path).
__global__ __launch_bounds__(128) void k_score(const float* __restrict__ R1t,
    const float* __restrict__ R2, const float* __restrict__ hs,
    const float* __restrict__ gumbel_u, float* __restrict__ score,
    float* __restrict__ snoisy){
  __shared__ float hsm[HH];
  __shared__ float red[128];
  int bt = blockIdx.x;
  int tid = threadIdx.x;
  for (int i = tid; i < HH; i += 128) hsm[i] = hs[(size_t)bt*HH + i];
  __syncthreads();
  float acc = 0.f;
  for (int k = 0; k < HH; ++k) acc += R1t[(size_t)k*RANKH + tid] * hsm[k];
  red[tid] = fmaxf(acc, 0.f) * R2[tid];
  __syncthreads();
  for (int s = 64; s > 0; s >>= 1){
    if (tid < s) red[tid] += red[tid+s];
    __syncthreads();
  }
  if (tid == 0){
    float s = red[0];
    float u = gumbel_u[bt];
    float noise = -logf(-logf(u));
    score[bt]  = s;
    snoisy[bt] = s + noise;
  }
}

// ---------------------------------------------------------------------------
// Build the tree structure for all batches. 1 block, 64 threads.
// level_count[0] <- number of levels (max height).
__global__ __launch_bounds__(64) void k_build(const float* __restrict__ score,
    const float* __restrict__ snoisy, const int* __restrict__ length,
    int* __restrict__ node_l, int* __restrict__ node_r, int* __restrict__ node_x,
    int* __restrict__ node_lvl, int* __restrict__ node_b, int* __restrict__ node_root,
    int* __restrict__ level_count, int* __restrict__ level_off, int* __restrict__ order){
  __shared__ float sc[BB*LL], sn[BB*LL];
  __shared__ int lcount[MAXLVL+1], lcur[MAXLVL+1], loff[MAXLVL+1];
  __shared__ int percnt[BB];
  int tid = threadIdx.x;
  for (int i = tid; i < BB*LL; i += 64){ sc[i] = score[i]; sn[i] = snoisy[i]; }
  for (int i = tid; i <= MAXLVL; i += 64){ lcount[i] = 0; lcur[i] = 0; }
  __syncthreads();
  if (tid < BB){
    int b = tid;
    int len = length[b];
    if (len > LL) len = LL;
    int qs[MAXN], qe[MAXN], qn[MAXN];
    int qh = 0, qt = 0, cnt = 0;
    int rootn = cnt++;
    qs[qt] = 0; qe[qt] = len; qn[qt] = rootn; qt++;
    while (qh < qt){
      int s0 = qs[qh], e0 = qe[qh], nid = qn[qh]; qh++;
      float best = sc[b*LL + s0]; int pos = s0;
      for (int t2 = s0+1; t2 < e0; ++t2){
        float v = sc[b*LL + t2];
        if (v > best){ best = v; pos = t2; }
      }
      float bestn = sn[b*LL + s0]; int js = s0;
      for (int t2 = s0+1; t2 < e0; ++t2){
        float v = sn[b*LL + t2];
        if (v > bestn){ bestn = v; js = t2; }
      }
      int gid = b*MAXN + nid;
      node_x[gid] = js;
      node_b[gid] = b;
      node_root[gid] = (nid == 0) ? 1 : 0;
      int ln = pos - s0, enc_l, enc_r;
      if (ln <= 0) enc_l = -1;
      else if (ln == 1) enc_l = 10000 + s0;
      else { int c2 = cnt++; enc_l = b*MAXN + c2; qs[qt]=s0; qe[qt]=pos; qn[qt]=c2; qt++; }
      int rn = e0 - (pos+1);
      if (rn <= 0) enc_r = -1;
      else if (rn == 1) enc_r = 10000 + (pos+1);
      else { int c2 = cnt++; enc_r = b*MAXN + c2; qs[qt]=pos+1; qe[qt]=e0; qn[qt]=c2; qt++; }
      node_l[gid] = enc_l; node_r[gid] = enc_r;
    }
    for (int i = cnt-1; i >= 0; --i){
      int gid = b*MAXN + i;
      int el = node_l[gid], er = node_r[gid];
      int llv = (el >= 0 && el < 10000) ? node_lvl[el] : 0;
      int rlv = (er >= 0 && er < 10000) ? node_lvl[er] : 0;
      node_lvl[gid] = 1 + (llv > rlv ? llv : rlv);
    }
    for (int i = 0; i < cnt; ++i) atomicAdd(&lcount[node_lvl[b*MAXN + i]], 1);
    percnt[b] = cnt;
  }
  __syncthreads();
  if (tid == 0){
    int off = 0, nlev = 0;
    for (int lv = 1; lv <= MAXLVL; ++lv){
      loff[lv] = off;
      level_off[lv] = off;
      level_count[lv] = lcount[lv];
      if (lcount[lv] > 0) nlev = lv;
      off += lcount[lv];
    }
    level_count[0] = nlev;
  }
  __syncthreads();
  if (tid < BB){
    int b = tid;
    int cnt = percnt[b];
    for (int i = 0; i < cnt; ++i){
      int gid = b*MAXN + i;
      int lv = node_lvl[gid];
      int p = atomicAdd(&lcur[lv], 1);
      order[loff[lv] + p] = gid;
    }
  }
}

// ---------------------------------------------------------------------------
// Persistent tree composition, centralized-flag barriers, NO wb/inv.
// Wc is LDS-RESIDENT: each of the 256 blocks owns 24 Wc rows (144KB, loaded
// once, XOR-swizzled). Per level every block computes its 24 gate columns for
// ALL nodes of the level; A-frags are L2-broadcast reads, B from LDS.
// Coherence protocol:
//  - gates: LLC stores (A) -> LLC loads (B)
//  - nodeH_bf / nodeC: LLC stores (B) -> normal cached first-reads later
//  - Wc_bf / hs_bf / order / node_*: read-only, cached.
__global__ __launch_bounds__(256, 1) void k_tree(
    const unsigned short* __restrict__ Wc_bf,
    const unsigned short* __restrict__ hs_bf,
    unsigned short* __restrict__ nodeH_bf,
    const unsigned short* __restrict__ zrow,
    const float* __restrict__ bc, const float* __restrict__ cs,
    float* __restrict__ nodeC,
    const int* __restrict__ node_l, const int* __restrict__ node_r,
    const int* __restrict__ node_x, const int* __restrict__ node_b,
    const int* __restrict__ node_root, const int* __restrict__ level_count,
    const int* __restrict__ level_off, const int* __restrict__ order,
    float* __restrict__ gates, float* __restrict__ out,
    unsigned* __restrict__ flags){
  __shared__ __align__(16) unsigned char wlds[24*6144];   // 144KB Wc slice
  __shared__ int ldsok[4];
  int tid = threadIdx.x;
  int lane = tid & 63;
  int wave = tid >> 6;
  int fr = lane & 15;          // fragment row (A: node slot, B: Wc row)
  int fkq = lane >> 4;         // k-quarter 0..3
  int fk  = fkq * 8;           // element offset within 32-elem k-chunk
  int fkb = fkq * 16;          // byte offset
  int swz = (fr & 7) << 4;     // XOR swizzle (G4: row-major stride-6144B tile)
  int base0 = fr * 6144;               // n-tile 0: rows 0..15
  int base1 = (16 + (fr & 7)) * 6144;  // n-tile 1: rows 16..23 (dup for fr>=8)
  int rg24 = blockIdx.x * 24;  // this block's 24 Wc rows / gate columns

  // ---- one-time: stage 24 Wc rows into LDS, swizzled ----
  for (int i = tid; i < 24*384; i += 256){
    int row = i / 384;
    int ch  = i - row*384;     // 16B chunk within row
    uint4 v = *(const uint4*)(Wc_bf + (size_t)(rg24 + row)*K3H + ch*8);
    *(uint4*)(wlds + row*6144 + ((ch*16) ^ ((row & 7) << 4))) = v;
  }
  __syncthreads();

  int nlev = level_count[0];
  unsigned ph = 0;
  for (int lvl = 1; lvl <= nlev; ++lvl){
    int n = level_count[lvl];
    int loffv = level_off[lvl];
    // ---- Phase A: all nodes x this block's 24 Wc rows, B from LDS ----
    int mtiles = (n + 15) >> 4;
    for (int mt = wave; mt < mtiles; mt += 4){
      int slot = mt*16 + fr;
      const unsigned short *pa0, *pa1, *pa2;
      if (slot < n){
        int gid = order[loffv + slot];
        int b = node_b[gid];
        int el = node_l[gid], er = node_r[gid], xt = node_x[gid];
        pa0 = (el < 0) ? zrow : (el >= 10000 ? hs_bf + (size_t)(b*LL + (el-10000))*HH
                                             : nodeH_bf + (size_t)el*HH);
        pa1 = (er < 0) ? zrow : (er >= 10000 ? hs_bf + (size_t)(b*LL + (er-10000))*HH
                                             : nodeH_bf + (size_t)er*HH);
        pa2 = hs_bf + (size_t)(b*LL + xt)*HH;
      } else { pa0 = zrow; pa1 = zrow; pa2 = zrow; }
      const unsigned short* pa[3] = {pa0, pa1, pa2};
      f32x4 acc0 = {0.f,0.f,0.f,0.f};
      f32x4 acc1 = {0.f,0.f,0.f,0.f};
      #pragma unroll
      for (int part = 0; part < 3; ++part){
        const unsigned short* ap = pa[part] + fk;
        #pragma unroll 8
        for (int kcc = 0; kcc < 1024; kcc += 32){
          bf16x8 a = *(const bf16x8*)(ap + kcc);
          int xb = part*2048 + kcc*2 + fkb;
          bf16x8 b0 = *(const bf16x8*)(wlds + base0 + (xb ^ swz));
          bf16x8 b1 = *(const bf16x8*)(wlds + base1 + (xb ^ swz));
          acc0 = __builtin_amdgcn_mfma_f32_16x16x32_bf16(a, b0, acc0, 0, 0, 0);
          acc1 = __builtin_amdgcn_mfma_f32_16x16x32_bf16(a, b1, acc1, 0, 0, 0);
        }
      }
      int m0 = mt*16 + fkq*4;
      #pragma unroll
      for (int r = 0; r < 4; ++r){
        int m = m0 + r;
        if (m < n){
          st_llc(&gates[(size_t)m*NG6 + rg24 + fr], acc0[r]);
          if (fr < 8)
            st_llc(&gates[(size_t)m*NG6 + rg24 + 16 + fr], acc1[r]);
        }
      }
    }
    ph++;
    flagbar(flags, ph, ldsok);
    // ---- Phase B: epilogue ----
    int items = n * 4;
    for (int it = blockIdx.x; it < items; it += 256){
      int ns = it >> 2;
      int j = (it & 3)*256 + tid;
      int gid = order[loffv + ns];
      int b = node_b[gid];
      int el = node_l[gid], er = node_r[gid], xt = node_x[gid];
      float gg[6];
      #pragma unroll
      for (int q = 0; q < 6; ++q)
        gg[q] = bc[q*HH + j] + ld_llc(&gates[(size_t)ns*NG6 + q*HH + j]);
      float lc = (el < 0) ? 0.f : (el >= 10000 ? cs[(size_t)(b*LL + (el-10000))*HH + j]
                                               : nodeC[(size_t)el*HH + j]);
      float rc = (er < 0) ? 0.f : (er >= 10000 ? cs[(size_t)(b*LL + (er-10000))*HH + j]
                                               : nodeC[(size_t)er*HH + j]);
      float xc = cs[(size_t)(b*LL + xt)*HH + j];
      float c = sigf(gg[0])*tanhf(gg[4]) + sigf(gg[1])*lc + sigf(gg[2])*rc + sigf(gg[3])*xc;
      float h = sigf(gg[5])*tanhf(c);
      st_llc_u16(&nodeH_bf[(size_t)gid*HH + j], (unsigned)f2bf(h));
      st_llc(&nodeC[(size_t)gid*HH + j], c);
      if (node_root[gid]){
        out[(size_t)b*HH + j] = h;
        out[(size_t)BB*HH + (size_t)b*HH + j] = c;
      }
    }
    if (lvl < nlev){
      ph++;
      flagbar(flags, ph, ldsok);
    }
  }
}

// ---------------------------------------------------------------------------
extern "C" void kernel_launch(void* const* d_in, const int* in_sizes, int n_in,
                              void* d_out, int out_size, void* d_ws, size_t ws_size,
                              hipStream_t stream){
  const float* se  = (const float*)d_in[0];
  const float* gu  = (const float*)d_in[1];
  const float* Wih = (const float*)d_in[2];
  const float* Whh = (const float*)d_in[3];
  const float* bih = (const float*)d_in[4];
  const float* bhh = (const float*)d_in[5];
  const float* R1  = (const float*)d_in[6];
  const float* R2  = (const float*)d_in[7];
  const float* Wc  = (const float*)d_in[8];
  const float* bc  = (const float*)d_in[9];
  const int*   len = (const int*)d_in[10];
  float* out = (float*)d_out;                 // [2,16,1024] fp32

  float* ws = (float*)d_ws;
  size_t off = 0;
  float* R1t   = ws + off; off += (size_t)HH*RANKH;
  float* Gx    = ws + off; off += (size_t)BB*LL*NG4;     // [m][t][4096]
  float* Gxt   = ws + off; off += (size_t)BB*LL*NG4;     // [t][4096][m]
  float* hs    = ws + off; off += (size_t)BB*LL*HH;
  float* cs    = ws + off; off += (size_t)BB*LL*HH;
  float* nodeC = ws + off; off += (size_t)TOTN*HH;
  float* gates = ws + off; off += (size_t)MAXNPL*NG6;
  unsigned short* Wc_bf    = (unsigned short*)(ws + off); off += (size_t)NG6*K3H/2;
  unsigned short* hs_bf    = (unsigned short*)(ws + off); off += (size_t)BB*LL*HH/2;
  unsigned short* nodeH_bf = (unsigned short*)(ws + off); off += (size_t)TOTN*HH/2 + 512;
  unsigned short* zrow     = (unsigned short*)(ws + off); off += 512;  // 1024 zero bf16
  float* score = ws + off; off += 1024;
  float* snoi  = ws + off; off += 1024;
  unsigned* flags = (unsigned*)(ws + off); off += 2*FDOM; // scan @0, tree @ +FDOM dwords (128KB)
  int* ib = (int*)(ws + off);
  int* node_l    = ib; ib += 768;
  int* node_r    = ib; ib += 768;
  int* node_x    = ib; ib += 768;
  int* node_lvl  = ib; ib += 768;
  int* node_b    = ib; ib += 768;
  int* node_root = ib; ib += 768;
  int* level_count = ib; ib += 64;
  int* level_off   = ib; ib += 64;
  int* order       = ib; ib += 768;

  // 0. zero flag arrays + dummy zero row (ws poisoned every launch)
  k_init<<<1, 256, 0, stream>>>(flags, zrow);
  // 1. R1 transpose + Wc bf16 conversion
  k_transpose<<<dim3(32, 4), dim3(32, 8), 0, stream>>>(R1, R1t, RANKH, HH);
  k_cvt_bf16<<<(NG6*K3H)/1024, 256, 0, stream>>>(Wc, Wc_bf, NG6*K3H);
  // 2. input-side gate GEMM (+ both biases), then transpose for the scan
  k_gemm_gx<<<dim3(12, 64), 256, 0, stream>>>(se, Wih, bih, bhh, Gx, BB*LL, NG4, HH);
  k_gx_t<<<dim3(48, 16), 256, 0, stream>>>(Gx, Gxt);
  // 3. persistent recurrent LSTM scan (48 steps, centralized barriers)
  k_lstm_scan<<<256, 256, 0, stream>>>(Whh, Gxt, hs, cs, hs_bf, flags);
  // 4. per-position scores + gumbel noise (fp32)
  k_score<<<BB*LL, 128, 0, stream>>>(R1t, R2, hs, gu, score, snoi);
  // 5. tree structure
  k_build<<<1, 64, 0, stream>>>(score, snoi, len, node_l, node_r, node_x,
                                node_lvl, node_b, node_root,
                                level_count, level_off, order);
  // 6. persistent level-by-level nary composition (LDS-resident Wc)
  k_tree<<<256, 256, 0, stream>>>(Wc_bf, hs_bf, nodeH_bf, zrow, bc, cs, nodeC,
                                  node_l, node_r, node_x, node_b, node_root,
                                  level_count, level_off, order,
                                  gates, out, flags + FDOM);
}